// Round 1
// baseline (420.230 us; speedup 1.0000x reference)
//
#include <hip/hip_runtime.h>
#include <cstddef>

#define SEQ 2048
#define DIM 1024
#define NH 16
#define HD 64
#define CK 64
#define NCK (SEQ / CK)          // 32 chunks
#define KVSZ (HD * HD + HD)     // 4160 floats per (head, chunk) state

__device__ __forceinline__ float phi_fn(float x) {
    // elu(x)+1 : x>0 ? x+1 : exp(x)
    return x > 0.f ? x + 1.f : __expf(x);
}

// ---------------- fp32 tiled GEMM: C = A(MxK) @ B(KxN), row-major ----------------
// Requires M%128==0, N%128==0, K%8==0 (true for all shapes here).
template<int BM, int BN, int BK>
__global__ __launch_bounds__(256)
void sgemm_tile(const float* __restrict__ A, const float* __restrict__ B,
                float* __restrict__ C, int M, int N, int K)
{
    __shared__ float As[BK][BM];   // A tile, transposed to [k][m]
    __shared__ float Bs[BK][BN];   // B tile [k][n]
    const int tid = threadIdx.x;
    const int tx = tid & 15, ty = tid >> 4;
    const int m0 = blockIdx.y * BM, n0 = blockIdx.x * BN;
    float acc[8][8] = {};
    for (int k0 = 0; k0 < K; k0 += BK) {
        {
            // A: 128 rows x 8 k -> each thread one float4
            const int r = tid >> 1, c = (tid & 1) * 4;
            float4 av = *(const float4*)&A[(size_t)(m0 + r) * K + k0 + c];
            As[c + 0][r] = av.x; As[c + 1][r] = av.y;
            As[c + 2][r] = av.z; As[c + 3][r] = av.w;
            // B: 8 k rows x 128 cols -> each thread one float4
            const int kr = tid >> 5, nc = (tid & 31) * 4;
            *(float4*)&Bs[kr][nc] = *(const float4*)&B[(size_t)(k0 + kr) * N + n0 + nc];
        }
        __syncthreads();
        #pragma unroll
        for (int kk = 0; kk < BK; ++kk) {
            float a[8], b[8];
            *(float4*)&a[0] = *(const float4*)&As[kk][ty * 8];
            *(float4*)&a[4] = *(const float4*)&As[kk][ty * 8 + 4];
            *(float4*)&b[0] = *(const float4*)&Bs[kk][tx * 8];
            *(float4*)&b[4] = *(const float4*)&Bs[kk][tx * 8 + 4];
            #pragma unroll
            for (int i = 0; i < 8; ++i)
                #pragma unroll
                for (int j = 0; j < 8; ++j)
                    acc[i][j] += a[i] * b[j];
        }
        __syncthreads();
    }
    #pragma unroll
    for (int i = 0; i < 8; ++i) {
        float4 v0 = make_float4(acc[i][0], acc[i][1], acc[i][2], acc[i][3]);
        float4 v1 = make_float4(acc[i][4], acc[i][5], acc[i][6], acc[i][7]);
        float* crow = &C[(size_t)(m0 + ty * 8 + i) * N + n0 + tx * 8];
        *(float4*)&crow[0] = v0;
        *(float4*)&crow[4] = v1;
    }
}

// ---------------- Phase A: per-(head,chunk) KV sums ----------------
// kvs[h][c][i*64+j]   = sum_{s in chunk} phi_k[s][i] * v[s][j]
// kvs[h][c][4096 + i] = sum_{s in chunk} phi_k[s][i]
__global__ __launch_bounds__(256)
void chunk_kv(const float* __restrict__ qkv, float* __restrict__ kvs)
{
    const int c = blockIdx.x, h = blockIdx.y;
    __shared__ float pk[CK][HD];
    __shared__ float vv[CK][HD];
    const int tid = threadIdx.x;
    const int s0 = c * CK;
    for (int idx = tid; idx < CK * HD; idx += 256) {
        const int r = idx >> 6, col = idx & 63;
        const size_t base = (size_t)(s0 + r) * (3 * DIM) + (size_t)h * HD + col;
        pk[r][col] = phi_fn(qkv[base + DIM]);      // k block
        vv[r][col] = qkv[base + 2 * DIM];          // v block
    }
    __syncthreads();
    const int i = tid >> 2, j0 = (tid & 3) * 16;
    float acc[16] = {};
    for (int s = 0; s < CK; ++s) {
        const float kv_ = pk[s][i];
        #pragma unroll
        for (int j = 0; j < 16; ++j) acc[j] += kv_ * vv[s][j0 + j];
    }
    float* dst = kvs + (size_t)(h * NCK + c) * KVSZ;
    #pragma unroll
    for (int j = 0; j < 16; ++j) dst[i * 64 + j0 + j] = acc[j];
    if (tid < HD) {
        float s_ = 0.f;
        for (int s = 0; s < CK; ++s) s_ += pk[s][tid];
        dst[HD * HD + tid] = s_;
    }
}

// ---------------- Phase B: exclusive prefix scan across chunks ----------------
__global__ __launch_bounds__(256)
void scan_kv(float* __restrict__ kvs)
{
    const int e = blockIdx.x * 256 + threadIdx.x;
    if (e >= NH * KVSZ) return;
    const int h = e / KVSZ, off = e % KVSZ;
    float run = 0.f;
    for (int c = 0; c < NCK; ++c) {
        float* p = kvs + (size_t)(h * NCK + c) * KVSZ + off;
        const float v = *p;
        *p = run;
        run += v;
    }
}

// ---------------- Phase C: per-(head,chunk) outputs ----------------
__global__ __launch_bounds__(256)
void attn_chunk(const float* __restrict__ qkv, const float* __restrict__ kvs,
                float* __restrict__ attn)
{
    const int c = blockIdx.x, h = blockIdx.y;
    __shared__ float pq[CK][HD];    // phi_q   [row][feat]
    __shared__ float pkT[HD][CK];   // phi_k^T [feat][row]
    __shared__ float vv[CK][HD];    // v       [row][col]
    __shared__ float P[CK][CK];     // intra-chunk scores (lower-tri)
    __shared__ float kvp[HD][HD];   // exclusive KV prefix [feat][col]
    __shared__ float ksp[HD];       // exclusive k-sum prefix
    __shared__ float dnm[CK];
    const int tid = threadIdx.x;
    const int s0 = c * CK;
    const float* kvrow = kvs + (size_t)(h * NCK + c) * KVSZ;

    for (int idx = tid; idx < CK * HD; idx += 256) {
        const int r = idx >> 6, col = idx & 63;
        const size_t base = (size_t)(s0 + r) * (3 * DIM) + (size_t)h * HD + col;
        pq[r][col]  = phi_fn(qkv[base]);
        pkT[col][r] = phi_fn(qkv[base + DIM]);
        vv[r][col]  = qkv[base + 2 * DIM];
        kvp[r][col] = kvrow[idx];
    }
    if (tid < HD) ksp[tid] = kvrow[HD * HD + tid];
    __syncthreads();

    const int r = tid >> 2, g0 = (tid & 3) * 16;

    // P[r][s] = phi_q[r] . phi_k[s]  (masked to s<=r)
    float pa[16] = {};
    for (int i = 0; i < HD; ++i) {
        const float qv = pq[r][i];
        float kv4[16];
        *(float4*)&kv4[0]  = *(const float4*)&pkT[i][g0];
        *(float4*)&kv4[4]  = *(const float4*)&pkT[i][g0 + 4];
        *(float4*)&kv4[8]  = *(const float4*)&pkT[i][g0 + 8];
        *(float4*)&kv4[12] = *(const float4*)&pkT[i][g0 + 12];
        #pragma unroll
        for (int t = 0; t < 16; ++t) pa[t] += qv * kv4[t];
    }
    #pragma unroll
    for (int t = 0; t < 16; ++t)
        P[r][g0 + t] = (g0 + t <= r) ? pa[t] : 0.f;
    __syncthreads();

    // denominator per row
    if (tid < CK) {
        float d = 1e-6f;
        for (int i = 0; i < HD; ++i) d += pq[tid][i] * ksp[i];
        for (int s = 0; s <= tid; ++s) d += P[tid][s];
        dnm[tid] = d;
    }
    __syncthreads();

    // numer[r][j] = sum_i phi_q[r][i]*KVp[i][j] + sum_{s<=r} P[r][s]*v[s][j]
    float oa[16] = {};
    for (int i = 0; i < HD; ++i) {
        const float qv = pq[r][i];
        float bv[16];
        *(float4*)&bv[0]  = *(const float4*)&kvp[i][g0];
        *(float4*)&bv[4]  = *(const float4*)&kvp[i][g0 + 4];
        *(float4*)&bv[8]  = *(const float4*)&kvp[i][g0 + 8];
        *(float4*)&bv[12] = *(const float4*)&kvp[i][g0 + 12];
        #pragma unroll
        for (int t = 0; t < 16; ++t) oa[t] += qv * bv[t];
    }
    for (int s = 0; s <= r; ++s) {
        const float pv = P[r][s];
        float bv[16];
        *(float4*)&bv[0]  = *(const float4*)&vv[s][g0];
        *(float4*)&bv[4]  = *(const float4*)&vv[s][g0 + 4];
        *(float4*)&bv[8]  = *(const float4*)&vv[s][g0 + 8];
        *(float4*)&bv[12] = *(const float4*)&vv[s][g0 + 12];
        #pragma unroll
        for (int t = 0; t < 16; ++t) oa[t] += pv * bv[t];
    }
    const float dinv = 1.f / dnm[r];
    float* dst = attn + (size_t)(s0 + r) * DIM + (size_t)h * HD + g0;
    #pragma unroll
    for (int t4 = 0; t4 < 4; ++t4) {
        *(float4*)&dst[t4 * 4] = make_float4(oa[t4 * 4 + 0] * dinv,
                                             oa[t4 * 4 + 1] * dinv,
                                             oa[t4 * 4 + 2] * dinv,
                                             oa[t4 * 4 + 3] * dinv);
    }
}

extern "C" void kernel_launch(void* const* d_in, const int* in_sizes, int n_in,
                              void* d_out, int out_size, void* d_ws, size_t ws_size,
                              hipStream_t stream)
{
    const float* x     = (const float*)d_in[0];
    // d_in[1] = causal_mask — implicit in the algorithm, unused
    const float* W_qkv = (const float*)d_in[2];
    const float* W_out = (const float*)d_in[3];
    float* out = (float*)d_out;

    char* ws = (char*)d_ws;
    float* qkv  = (float*)(ws);                                   // 2048*3072 f32 = 25.2 MB
    float* attn = (float*)(ws + (size_t)SEQ * 3 * DIM * 4);       // 2048*1024 f32 = 8.4 MB
    float* kvs  = (float*)(ws + (size_t)SEQ * 3 * DIM * 4
                              + (size_t)SEQ * DIM * 4);           // 16*32*4160 f32 = 8.5 MB

    dim3 blk(256);

    // qkv = x @ W_qkv   (2048x1024 @ 1024x3072)
    sgemm_tile<128, 128, 8><<<dim3(3 * DIM / 128, SEQ / 128), blk, 0, stream>>>(
        x, W_qkv, qkv, SEQ, 3 * DIM, DIM);

    // per-chunk KV sums, then exclusive scan across chunks
    chunk_kv<<<dim3(NCK, NH), blk, 0, stream>>>(qkv, kvs);
    scan_kv<<<dim3((NH * KVSZ + 255) / 256), blk, 0, stream>>>(kvs);

    // per-chunk attention outputs
    attn_chunk<<<dim3(NCK, NH), blk, 0, stream>>>(qkv, kvs, attn);

    // out = attn @ W_out  (2048x1024 @ 1024x1024)
    sgemm_tile<128, 128, 8><<<dim3(DIM / 128, SEQ / 128), blk, 0, stream>>>(
        attn, W_out, out, SEQ, DIM, DIM);
}

// Round 2
// 109.517 us; speedup vs baseline: 3.8371x; 3.8371x over previous
//
#include <hip/hip_runtime.h>
#include <cstddef>
#include <cstdint>

#define SEQ 2048
#define DIM 1024
#define NH 16
#define HD 64
#define CK 64
#define NCK (SEQ / CK)          // 32 chunks
#define KVSZ (HD * HD + HD)     // 4160 floats per (head, chunk) state

typedef __attribute__((ext_vector_type(8))) short short8;   // 8 bf16 (4 VGPRs)
typedef __attribute__((ext_vector_type(4))) float fx4;      // 4 fp32 acc

__device__ __forceinline__ float phi_fn(float x) {
    return x > 0.f ? x + 1.f : __expf(x);   // elu(x)+1
}
__device__ __forceinline__ float bf2f(unsigned short u) {
    return __uint_as_float((unsigned int)u << 16);
}
__device__ __forceinline__ unsigned short f2bf(float f) {
    unsigned int u = __float_as_uint(f);
    unsigned int r = (u + 0x7FFFu + ((u >> 16) & 1u)) >> 16;   // RNE
    return (unsigned short)r;
}

// ---------------- fp32 -> bf16 elementwise ----------------
__global__ __launch_bounds__(256)
void to_bf16_vec(const float* __restrict__ in, unsigned short* __restrict__ out, int n)
{
    const int i = (blockIdx.x * 256 + threadIdx.x) * 4;
    if (i >= n) return;
    float4 v = *(const float4*)&in[i];
    ushort4 o;
    o.x = f2bf(v.x); o.y = f2bf(v.y); o.z = f2bf(v.z); o.w = f2bf(v.w);
    *(ushort4*)&out[i] = o;
}

// ---------------- W (KxN f32) -> WT (NxK bf16) ----------------
__global__ __launch_bounds__(256)
void transpose_to_bf16(const float* __restrict__ W, unsigned short* __restrict__ WT,
                       int K, int N)
{
    __shared__ float t[32][33];
    const int kb = blockIdx.y * 32, nb = blockIdx.x * 32;
    const int c = threadIdx.x & 31, r0 = threadIdx.x >> 5;   // 32 cols x 8 rows
    #pragma unroll
    for (int i = 0; i < 4; ++i) {
        const int r = r0 + i * 8;
        t[r][c] = W[(size_t)(kb + r) * N + nb + c];
    }
    __syncthreads();
    #pragma unroll
    for (int i = 0; i < 4; ++i) {
        const int r = r0 + i * 8;
        WT[(size_t)(nb + r) * K + kb + c] = f2bf(t[c][r]);
    }
}

// ---------------- bf16 MFMA GEMM: C(MxN) = A(MxK) @ BT(NxK)^T ----------------
// 128x128 tile, BK=64, 256 threads (4 waves, 2x2 of 64x64), 16x16x32 MFMA.
// LDS staged via global_load_lds(16B) with pre-swizzled SOURCE (linear dest),
// reads XOR-swizzled: byte ^= (row&7)<<4  -> conflict-free ds_read_b128.
__device__ __forceinline__ void stage_tile(const unsigned short* __restrict__ src,
                                           unsigned short* lds_base, int K, int k0,
                                           int tid)
{
    const int wave = tid >> 6, lane = tid & 63;
    #pragma unroll
    for (int i = 0; i < 4; ++i) {
        const int chunk = wave * 4 + i;                // wave-uniform
        const int L = chunk * 1024 + lane * 16;        // linear dest byte
        const int row = L >> 7;                        // 128 B per row (64 bf16)
        const int srcb = L ^ ((row & 7) << 4);         // inverse swizzle on source
        const int col = (srcb & 127) >> 1;
        const unsigned short* g = src + (size_t)row * K + k0 + col;
        __builtin_amdgcn_global_load_lds(
            (const __attribute__((address_space(1))) void*)g,
            (__attribute__((address_space(3))) void*)((char*)lds_base + chunk * 1024),
            16, 0, 0);
    }
}

__device__ __forceinline__ short8 read_frag(const unsigned short* lds_base,
                                            int row, int kcol)
{
    int byte = row * 128 + kcol * 2;
    byte ^= (row & 7) << 4;
    return *(const short8*)((const char*)lds_base + byte);
}

template<int OUT_BF16>
__global__ __launch_bounds__(256)
void gemm_bf16(const unsigned short* __restrict__ A,
               const unsigned short* __restrict__ BT,
               void* __restrict__ Cout, int M, int N, int K)
{
    __shared__ unsigned short As[128 * 64];
    __shared__ unsigned short Bs[128 * 64];
    const int tid = threadIdx.x;
    const int lane = tid & 63, wave = tid >> 6;
    const int wm = (wave >> 1) * 64, wn = (wave & 1) * 64;
    const int m0 = blockIdx.y * 128, n0 = blockIdx.x * 128;
    fx4 acc[4][4] = {};

    const unsigned short* Abase = A + (size_t)m0 * K;
    const unsigned short* Bbase = BT + (size_t)n0 * K;

    for (int k0 = 0; k0 < K; k0 += 64) {
        stage_tile(Abase, As, K, k0, tid);
        stage_tile(Bbase, Bs, K, k0, tid);
        __syncthreads();   // compiler drains vmcnt before s_barrier
        #pragma unroll
        for (int ks = 0; ks < 2; ++ks) {
            short8 af[4], bfr[4];
            #pragma unroll
            for (int i = 0; i < 4; ++i) {
                af[i]  = read_frag(As, wm + i * 16 + (lane & 15), ks * 32 + (lane >> 4) * 8);
                bfr[i] = read_frag(Bs, wn + i * 16 + (lane & 15), ks * 32 + (lane >> 4) * 8);
            }
            #pragma unroll
            for (int i = 0; i < 4; ++i)
                #pragma unroll
                for (int j = 0; j < 4; ++j)
                    acc[i][j] = __builtin_amdgcn_mfma_f32_16x16x32_bf16(
                        af[i], bfr[j], acc[i][j], 0, 0, 0);
        }
        __syncthreads();
    }

    // C/D layout: col = lane&15, row = (lane>>4)*4 + reg
    const int cr = (lane >> 4) * 4, cc = lane & 15;
    #pragma unroll
    for (int i = 0; i < 4; ++i)
        #pragma unroll
        for (int j = 0; j < 4; ++j) {
            const int m = m0 + wm + i * 16 + cr;
            const int n = n0 + wn + j * 16 + cc;
            #pragma unroll
            for (int r = 0; r < 4; ++r) {
                const float v = acc[i][j][r];
                if (OUT_BF16)
                    ((unsigned short*)Cout)[(size_t)(m + r) * N + n] = f2bf(v);
                else
                    ((float*)Cout)[(size_t)(m + r) * N + n] = v;
            }
        }
}

// ---------------- Phase A: per-(head,chunk) KV sums ----------------
__global__ __launch_bounds__(256)
void chunk_kv(const unsigned short* __restrict__ qkv, float* __restrict__ kvs)
{
    const int c = blockIdx.x, h = blockIdx.y;
    __shared__ float pk[CK][HD];
    __shared__ float vv[CK][HD];
    const int tid = threadIdx.x;
    const int s0 = c * CK;
    for (int idx = tid * 4; idx < CK * HD; idx += 1024) {
        const int r = idx >> 6, col = idx & 63;
        const size_t base = (size_t)(s0 + r) * (3 * DIM) + (size_t)h * HD + col;
        ushort4 kk = *(const ushort4*)&qkv[base + DIM];
        ushort4 v4 = *(const ushort4*)&qkv[base + 2 * DIM];
        pk[r][col + 0] = phi_fn(bf2f(kk.x)); pk[r][col + 1] = phi_fn(bf2f(kk.y));
        pk[r][col + 2] = phi_fn(bf2f(kk.z)); pk[r][col + 3] = phi_fn(bf2f(kk.w));
        vv[r][col + 0] = bf2f(v4.x); vv[r][col + 1] = bf2f(v4.y);
        vv[r][col + 2] = bf2f(v4.z); vv[r][col + 3] = bf2f(v4.w);
    }
    __syncthreads();
    const int i = tid >> 2, j0 = (tid & 3) * 16;
    float acc[16] = {};
    for (int s = 0; s < CK; ++s) {
        const float kv_ = pk[s][i];
        #pragma unroll
        for (int j = 0; j < 16; ++j) acc[j] += kv_ * vv[s][j0 + j];
    }
    float* dst = kvs + (size_t)(h * NCK + c) * KVSZ;
    #pragma unroll
    for (int j = 0; j < 16; ++j) dst[i * 64 + j0 + j] = acc[j];
    if (tid < HD) {
        float s_ = 0.f;
        for (int s = 0; s < CK; ++s) s_ += pk[s][tid];
        dst[HD * HD + tid] = s_;
    }
}

// ---------------- Phase B: exclusive prefix scan across chunks ----------------
__global__ __launch_bounds__(256)
void scan_kv(float* __restrict__ kvs)
{
    const int e = blockIdx.x * 256 + threadIdx.x;
    if (e >= NH * KVSZ) return;
    const int h = e / KVSZ, off = e % KVSZ;
    float run = 0.f;
    for (int c = 0; c < NCK; ++c) {
        float* p = kvs + (size_t)(h * NCK + c) * KVSZ + off;
        const float v = *p;
        *p = run;
        run += v;
    }
}

// ---------------- Phase C: per-(head,chunk) outputs (bf16 out) ----------------
__global__ __launch_bounds__(256)
void attn_chunk(const unsigned short* __restrict__ qkv, const float* __restrict__ kvs,
                unsigned short* __restrict__ attn)
{
    const int c = blockIdx.x, h = blockIdx.y;
    __shared__ float pq[CK][HD];
    __shared__ float pkT[HD][CK];
    __shared__ float vv[CK][HD];
    __shared__ float P[CK][CK];
    __shared__ float kvp[HD][HD];
    __shared__ float ksp[HD];
    __shared__ float dnm[CK];
    const int tid = threadIdx.x;
    const int s0 = c * CK;
    const float* kvrow = kvs + (size_t)(h * NCK + c) * KVSZ;

    for (int idx = tid * 4; idx < CK * HD; idx += 1024) {
        const int r = idx >> 6, col = idx & 63;
        const size_t base = (size_t)(s0 + r) * (3 * DIM) + (size_t)h * HD + col;
        ushort4 qq = *(const ushort4*)&qkv[base];
        ushort4 kk = *(const ushort4*)&qkv[base + DIM];
        ushort4 v4 = *(const ushort4*)&qkv[base + 2 * DIM];
        pq[r][col + 0] = phi_fn(bf2f(qq.x)); pq[r][col + 1] = phi_fn(bf2f(qq.y));
        pq[r][col + 2] = phi_fn(bf2f(qq.z)); pq[r][col + 3] = phi_fn(bf2f(qq.w));
        pkT[col + 0][r] = phi_fn(bf2f(kk.x)); pkT[col + 1][r] = phi_fn(bf2f(kk.y));
        pkT[col + 2][r] = phi_fn(bf2f(kk.z)); pkT[col + 3][r] = phi_fn(bf2f(kk.w));
        vv[r][col + 0] = bf2f(v4.x); vv[r][col + 1] = bf2f(v4.y);
        vv[r][col + 2] = bf2f(v4.z); vv[r][col + 3] = bf2f(v4.w);
        *(float4*)&((float*)kvp)[idx] = *(const float4*)&kvrow[idx];
    }
    if (tid < HD) ksp[tid] = kvrow[HD * HD + tid];
    __syncthreads();

    const int r = tid >> 2, g0 = (tid & 3) * 16;

    float pa[16] = {};
    for (int i = 0; i < HD; ++i) {
        const float qv = pq[r][i];
        float kv4[16];
        *(float4*)&kv4[0]  = *(const float4*)&pkT[i][g0];
        *(float4*)&kv4[4]  = *(const float4*)&pkT[i][g0 + 4];
        *(float4*)&kv4[8]  = *(const float4*)&pkT[i][g0 + 8];
        *(float4*)&kv4[12] = *(const float4*)&pkT[i][g0 + 12];
        #pragma unroll
        for (int t = 0; t < 16; ++t) pa[t] += qv * kv4[t];
    }
    #pragma unroll
    for (int t = 0; t < 16; ++t)
        P[r][g0 + t] = (g0 + t <= r) ? pa[t] : 0.f;
    __syncthreads();

    if (tid < CK) {
        float d = 1e-6f;
        for (int i = 0; i < HD; ++i) d += pq[tid][i] * ksp[i];
        for (int s = 0; s <= tid; ++s) d += P[tid][s];
        dnm[tid] = d;
    }
    __syncthreads();

    float oa[16] = {};
    for (int i = 0; i < HD; ++i) {
        const float qv = pq[r][i];
        float bv[16];
        *(float4*)&bv[0]  = *(const float4*)&kvp[i][g0];
        *(float4*)&bv[4]  = *(const float4*)&kvp[i][g0 + 4];
        *(float4*)&bv[8]  = *(const float4*)&kvp[i][g0 + 8];
        *(float4*)&bv[12] = *(const float4*)&kvp[i][g0 + 12];
        #pragma unroll
        for (int t = 0; t < 16; ++t) oa[t] += qv * bv[t];
    }
    for (int s = 0; s <= r; ++s) {
        const float pv = P[r][s];
        float bv[16];
        *(float4*)&bv[0]  = *(const float4*)&vv[s][g0];
        *(float4*)&bv[4]  = *(const float4*)&vv[s][g0 + 4];
        *(float4*)&bv[8]  = *(const float4*)&vv[s][g0 + 8];
        *(float4*)&bv[12] = *(const float4*)&vv[s][g0 + 12];
        #pragma unroll
        for (int t = 0; t < 16; ++t) oa[t] += pv * bv[t];
    }
    const float dinv = 1.f / dnm[r];
    unsigned short* dst = attn + (size_t)(s0 + r) * DIM + (size_t)h * HD + g0;
    #pragma unroll
    for (int t4 = 0; t4 < 4; ++t4) {
        ushort4 o;
        o.x = f2bf(oa[t4 * 4 + 0] * dinv);
        o.y = f2bf(oa[t4 * 4 + 1] * dinv);
        o.z = f2bf(oa[t4 * 4 + 2] * dinv);
        o.w = f2bf(oa[t4 * 4 + 3] * dinv);
        *(ushort4*)&dst[t4 * 4] = o;
    }
}

extern "C" void kernel_launch(void* const* d_in, const int* in_sizes, int n_in,
                              void* d_out, int out_size, void* d_ws, size_t ws_size,
                              hipStream_t stream)
{
    const float* x     = (const float*)d_in[0];
    const float* W_qkv = (const float*)d_in[2];
    const float* W_out = (const float*)d_in[3];
    float* out = (float*)d_out;

    char* ws = (char*)d_ws;
    size_t off = 0;
    unsigned short* qkvb  = (unsigned short*)(ws + off); off += (size_t)SEQ * 3 * DIM * 2;  // 12.6 MB
    unsigned short* attnb = (unsigned short*)(ws + off); off += (size_t)SEQ * DIM * 2;      //  4.2 MB
    float*          kvs   = (float*)         (ws + off); off += (size_t)NH * NCK * KVSZ * 4;//  8.5 MB
    unsigned short* xb    = (unsigned short*)(ws + off); off += (size_t)SEQ * DIM * 2;      //  4.2 MB
    unsigned short* wqt   = (unsigned short*)(ws + off); off += (size_t)3 * DIM * DIM * 2;  //  6.3 MB
    unsigned short* wot   = (unsigned short*)(ws + off); off += (size_t)DIM * DIM * 2;      //  2.1 MB

    dim3 blk(256);

    to_bf16_vec<<<dim3(SEQ * DIM / 1024), blk, 0, stream>>>(x, xb, SEQ * DIM);
    transpose_to_bf16<<<dim3(3 * DIM / 32, DIM / 32), blk, 0, stream>>>(W_qkv, wqt, DIM, 3 * DIM);
    transpose_to_bf16<<<dim3(DIM / 32, DIM / 32), blk, 0, stream>>>(W_out, wot, DIM, DIM);

    gemm_bf16<1><<<dim3(3 * DIM / 128, SEQ / 128), blk, 0, stream>>>(
        xb, wqt, qkvb, SEQ, 3 * DIM, DIM);

    chunk_kv<<<dim3(NCK, NH), blk, 0, stream>>>(qkvb, kvs);
    scan_kv<<<dim3(NH * KVSZ / 256), blk, 0, stream>>>(kvs);
    attn_chunk<<<dim3(NCK, NH), blk, 0, stream>>>(qkvb, kvs, attnb);

    gemm_bf16<0><<<dim3(DIM / 128, SEQ / 128), blk, 0, stream>>>(
        attnb, wot, out, SEQ, DIM, DIM);
}

// Round 3
// 81.157 us; speedup vs baseline: 5.1780x; 1.3494x over previous
//
#include <hip/hip_runtime.h>
#include <cstddef>
#include <cstdint>

#define SEQ 2048
#define DIM 1024
#define NH 16
#define HD 64
#define CK 64
#define NCK (SEQ / CK)     // 32 chunks
#define KVR 65             // KV^T rows incl. ksum row
#define KVRP 80            // padded to 5 MFMA tiles

typedef __attribute__((ext_vector_type(8))) short short8;            // 8 bf16
typedef __attribute__((ext_vector_type(8))) unsigned short ushort8;  // 8 raw bf16
typedef __attribute__((ext_vector_type(4))) float fx4;

__device__ __forceinline__ float phi_fn(float x) {
    return x > 0.f ? x + 1.f : __expf(x);   // elu(x)+1
}
__device__ __forceinline__ float bf2f(unsigned short u) {
    return __uint_as_float((unsigned int)u << 16);
}
__device__ __forceinline__ unsigned short f2bf(float f) {
    unsigned int u = __float_as_uint(f);
    unsigned int r = (u + 0x7FFFu + ((u >> 16) & 1u)) >> 16;   // RNE
    return (unsigned short)r;
}

// ---- swizzled LDS helpers: all arrays have 64-ushort (128 B) row stride ----
// byte ^= (row&7)<<4 spreads same-column rows across 8 bank groups (G4 fix).
__device__ __forceinline__ void lds_write16(unsigned short* base, int row, int col, short8 v) {
    int byte = row * 128 + col * 2; byte ^= (row & 7) << 4;
    *(short8*)((char*)base + byte) = v;
}
__device__ __forceinline__ void lds_write2(unsigned short* base, int row, int col, unsigned short v) {
    int byte = row * 128 + col * 2; byte ^= (row & 7) << 4;
    *(unsigned short*)((char*)base + byte) = v;
}
__device__ __forceinline__ short8 lds_read_frag(const unsigned short* base, int row, int kcol) {
    int byte = row * 128 + kcol * 2; byte ^= (row & 7) << 4;
    return *(const short8*)((const char*)base + byte);
}

// ---------------- fp32 -> bf16 elementwise ----------------
__global__ __launch_bounds__(256)
void to_bf16_vec(const float* __restrict__ in, unsigned short* __restrict__ out, int n)
{
    const int i = (blockIdx.x * 256 + threadIdx.x) * 4;
    if (i >= n) return;
    float4 v = *(const float4*)&in[i];
    ushort4 o;
    o.x = f2bf(v.x); o.y = f2bf(v.y); o.z = f2bf(v.z); o.w = f2bf(v.w);
    *(ushort4*)&out[i] = o;
}

// ---------------- W (KxN f32) -> WT (NxK bf16) ----------------
__global__ __launch_bounds__(256)
void transpose_to_bf16(const float* __restrict__ W, unsigned short* __restrict__ WT,
                       int K, int N)
{
    __shared__ float t[32][33];
    const int kb = blockIdx.y * 32, nb = blockIdx.x * 32;
    const int c = threadIdx.x & 31, r0 = threadIdx.x >> 5;
    #pragma unroll
    for (int i = 0; i < 4; ++i) {
        const int r = r0 + i * 8;
        t[r][c] = W[(size_t)(kb + r) * N + nb + c];
    }
    __syncthreads();
    #pragma unroll
    for (int i = 0; i < 4; ++i) {
        const int r = r0 + i * 8;
        WT[(size_t)(nb + r) * K + kb + c] = f2bf(t[c][r]);
    }
}

// ---------------- bf16 MFMA GEMM: C(MxN) = A(MxK) @ BT(NxK)^T ----------------
__device__ __forceinline__ void stage_tile(const unsigned short* __restrict__ src,
                                           unsigned short* lds_base, int K, int k0,
                                           int tid)
{
    const int wave = tid >> 6, lane = tid & 63;
    #pragma unroll
    for (int i = 0; i < 4; ++i) {
        const int chunk = wave * 4 + i;
        const int L = chunk * 1024 + lane * 16;        // linear dest byte
        const int row = L >> 7;
        const int srcb = L ^ ((row & 7) << 4);         // inverse swizzle on source
        const int col = (srcb & 127) >> 1;
        const unsigned short* g = src + (size_t)row * K + k0 + col;
        __builtin_amdgcn_global_load_lds(
            (const __attribute__((address_space(1))) void*)g,
            (__attribute__((address_space(3))) void*)((char*)lds_base + chunk * 1024),
            16, 0, 0);
    }
}

template<int OUT_BF16>
__global__ __launch_bounds__(256)
void gemm_bf16(const unsigned short* __restrict__ A,
               const unsigned short* __restrict__ BT,
               void* __restrict__ Cout, int M, int N, int K)
{
    __shared__ unsigned short As[128 * 64];
    __shared__ unsigned short Bs[128 * 64];
    const int tid = threadIdx.x;
    const int lane = tid & 63, wave = tid >> 6;
    const int wm = (wave >> 1) * 64, wn = (wave & 1) * 64;
    const int m0 = blockIdx.y * 128, n0 = blockIdx.x * 128;
    fx4 acc[4][4] = {};

    const unsigned short* Abase = A + (size_t)m0 * K;
    const unsigned short* Bbase = BT + (size_t)n0 * K;

    for (int k0 = 0; k0 < K; k0 += 64) {
        stage_tile(Abase, As, K, k0, tid);
        stage_tile(Bbase, Bs, K, k0, tid);
        __syncthreads();
        #pragma unroll
        for (int ks = 0; ks < 2; ++ks) {
            short8 af[4], bfr[4];
            #pragma unroll
            for (int i = 0; i < 4; ++i) {
                af[i]  = lds_read_frag(As, wm + i * 16 + (lane & 15), ks * 32 + (lane >> 4) * 8);
                bfr[i] = lds_read_frag(Bs, wn + i * 16 + (lane & 15), ks * 32 + (lane >> 4) * 8);
            }
            #pragma unroll
            for (int i = 0; i < 4; ++i)
                #pragma unroll
                for (int j = 0; j < 4; ++j)
                    acc[i][j] = __builtin_amdgcn_mfma_f32_16x16x32_bf16(
                        af[i], bfr[j], acc[i][j], 0, 0, 0);
        }
        __syncthreads();
    }

    const int cr = (lane >> 4) * 4, cc = lane & 15;
    #pragma unroll
    for (int i = 0; i < 4; ++i)
        #pragma unroll
        for (int j = 0; j < 4; ++j) {
            const int m = m0 + wm + i * 16 + cr;
            const int n = n0 + wn + j * 16 + cc;
            #pragma unroll
            for (int r = 0; r < 4; ++r) {
                const float v = acc[i][j][r];
                if (OUT_BF16)
                    ((unsigned short*)Cout)[(size_t)(m + r) * N + n] = f2bf(v);
                else
                    ((float*)Cout)[(size_t)(m + r) * N + n] = v;
            }
        }
}

// ---------------- Phase A: per-(head,chunk) KV^T sums via MFMA ----------------
// kvs[h][c][j][i] = sum_s V[s][j]*phi_k[s][i]  (j<64);  row j=64 = ksum[i]
__global__ __launch_bounds__(256)
void chunk_kv(const unsigned short* __restrict__ qkv, float* __restrict__ kvs)
{
    const int c = blockIdx.x, h = blockIdx.y;
    __shared__ unsigned short kT[64 * 64];    // [i=d][s], swizzled
    __shared__ unsigned short vT[KVRP * 64];  // [j][s], row64=ones, 65-79=0
    const int tid = threadIdx.x, lane = tid & 63, wave = tid >> 6;
    const int s0 = c * CK;

    #pragma unroll
    for (int part = 0; part < 2; ++part) {
        const int s = (tid >> 3) + part * 32;
        const int d0 = (tid & 7) * 8;
        const size_t base = (size_t)(s0 + s) * (3 * DIM) + (size_t)h * HD + d0;
        ushort8 kk = *(const ushort8*)&qkv[base + DIM];
        ushort8 vv = *(const ushort8*)&qkv[base + 2 * DIM];
        #pragma unroll
        for (int u = 0; u < 8; ++u) {
            lds_write2(kT, d0 + u, s, f2bf(phi_fn(bf2f(kk[u]))));
            lds_write2(vT, d0 + u, s, vv[u]);
        }
    }
    if (tid < 64) lds_write2(vT, 64, tid, 0x3F80);   // bf16 1.0
    for (int idx = tid; idx < 15 * 64; idx += 256)
        lds_write2(vT, 65 + (idx >> 6), idx & 63, 0);
    __syncthreads();

    // C[j][i] over i in [16w,16w+16), all 80 j-rows
    fx4 acc[5] = {};
    #pragma unroll
    for (int ks = 0; ks < 2; ++ks) {
        short8 b = lds_read_frag(kT, wave * 16 + (lane & 15), ks * 32 + (lane >> 4) * 8);
        #pragma unroll
        for (int mt = 0; mt < 5; ++mt) {
            short8 a = lds_read_frag(vT, mt * 16 + (lane & 15), ks * 32 + (lane >> 4) * 8);
            acc[mt] = __builtin_amdgcn_mfma_f32_16x16x32_bf16(a, b, acc[mt], 0, 0, 0);
        }
    }
    float* dst = kvs + (size_t)(h * NCK + c) * KVR * 64;
    const int i = wave * 16 + (lane & 15);
    #pragma unroll
    for (int mt = 0; mt < 5; ++mt)
        #pragma unroll
        for (int t = 0; t < 4; ++t) {
            const int j = mt * 16 + (lane >> 4) * 4 + t;
            if (j < KVR) dst[(size_t)j * 64 + i] = acc[mt][t];
        }
}

// ---------------- Phase B: exclusive prefix scan (ILP loads), bf16 out -------
__global__ __launch_bounds__(256)
void scan_kv(const float* __restrict__ kvs, unsigned short* __restrict__ kvpb)
{
    const int e = blockIdx.x * 256 + threadIdx.x;
    if (e >= NH * KVR * 64) return;
    const int h = e / (KVR * 64), off = e % (KVR * 64);
    const float* src = kvs + (size_t)h * NCK * KVR * 64 + off;
    unsigned short* dst = kvpb + (size_t)h * NCK * KVR * 64 + off;
    float v[NCK];
    #pragma unroll
    for (int c2 = 0; c2 < NCK; ++c2) v[c2] = src[(size_t)c2 * KVR * 64];
    float run = 0.f;
    #pragma unroll
    for (int c2 = 0; c2 < NCK; ++c2) {
        dst[(size_t)c2 * KVR * 64] = f2bf(run);
        run += v[c2];
    }
}

// ---------------- Phase C: per-(head,chunk) outputs via MFMA ----------------
__global__ __launch_bounds__(256)
void attn_chunk(const unsigned short* __restrict__ qkv,
                const unsigned short* __restrict__ kvpb,
                unsigned short* __restrict__ attnb)
{
    const int c = blockIdx.x, h = blockIdx.y;
    __shared__ unsigned short q_s[64 * 64];   // phi_q [r][d]
    __shared__ unsigned short k_s[64 * 64];   // phi_k [s][d]
    __shared__ unsigned short p_s[64 * 64];   // masked P bf16 [r][s]
    __shared__ unsigned short vT[KVRP * 64];  // V^T [j][s], row64=ones
    __shared__ unsigned short kvp[KVRP * 64]; // KVp^T_aug [j][d], row64=ksp
    const int tid = threadIdx.x, lane = tid & 63, wave = tid >> 6;
    const int s0 = c * CK;

    #pragma unroll
    for (int part = 0; part < 2; ++part) {
        const int s = (tid >> 3) + part * 32;
        const int d0 = (tid & 7) * 8;
        const size_t base = (size_t)(s0 + s) * (3 * DIM) + (size_t)h * HD + d0;
        ushort8 qq = *(const ushort8*)&qkv[base];
        ushort8 kk = *(const ushort8*)&qkv[base + DIM];
        ushort8 vv = *(const ushort8*)&qkv[base + 2 * DIM];
        short8 qo, ko;
        #pragma unroll
        for (int u = 0; u < 8; ++u) {
            qo[u] = (short)f2bf(phi_fn(bf2f(qq[u])));
            ko[u] = (short)f2bf(phi_fn(bf2f(kk[u])));
        }
        lds_write16(q_s, s, d0, qo);
        lds_write16(k_s, s, d0, ko);
        #pragma unroll
        for (int u = 0; u < 8; ++u)
            lds_write2(vT, d0 + u, s, vv[u]);
    }
    const unsigned short* kv_src = kvpb + (size_t)(h * NCK + c) * KVR * 64;
    for (int idx = tid * 8; idx < KVR * 64; idx += 2048) {
        ushort8 kv8 = *(const ushort8*)&kv_src[idx];
        short8 kv8s;
        #pragma unroll
        for (int u = 0; u < 8; ++u) kv8s[u] = (short)kv8[u];
        lds_write16(kvp, idx >> 6, idx & 63, kv8s);
    }
    if (tid < 64) lds_write2(vT, 64, tid, 0x3F80);
    for (int idx = tid; idx < 15 * 64; idx += 256) {
        lds_write2(vT, 65 + (idx >> 6), idx & 63, 0);
        lds_write2(kvp, 65 + (idx >> 6), idx & 63, 0);
    }
    __syncthreads();

    const int r0 = wave * 16;
    // P = phi_q @ phi_k^T for rows [r0, r0+16)
    fx4 accp[4] = {};
    #pragma unroll
    for (int ks = 0; ks < 2; ++ks) {
        short8 aq = lds_read_frag(q_s, r0 + (lane & 15), ks * 32 + (lane >> 4) * 8);
        #pragma unroll
        for (int nt = 0; nt < 4; ++nt) {
            short8 bk = lds_read_frag(k_s, nt * 16 + (lane & 15), ks * 32 + (lane >> 4) * 8);
            accp[nt] = __builtin_amdgcn_mfma_f32_16x16x32_bf16(aq, bk, accp[nt], 0, 0, 0);
        }
    }
    // masked bf16 store (wave-local rows)
    #pragma unroll
    for (int nt = 0; nt < 4; ++nt)
        #pragma unroll
        for (int t = 0; t < 4; ++t) {
            const int r = r0 + (lane >> 4) * 4 + t, sc = nt * 16 + (lane & 15);
            lds_write2(p_s, r, sc, (sc <= r) ? f2bf(accp[nt][t]) : (unsigned short)0);
        }
    __syncthreads();

    // O[r][j] = Pm @ V_aug + phi_q @ KVp^T_aug   (col 64 = denominator)
    fx4 acc[5] = {};
    #pragma unroll
    for (int ks = 0; ks < 2; ++ks) {
        short8 ap = lds_read_frag(p_s, r0 + (lane & 15), ks * 32 + (lane >> 4) * 8);
        short8 aq = lds_read_frag(q_s, r0 + (lane & 15), ks * 32 + (lane >> 4) * 8);
        #pragma unroll
        for (int nt = 0; nt < 5; ++nt) {
            short8 bv  = lds_read_frag(vT,  nt * 16 + (lane & 15), ks * 32 + (lane >> 4) * 8);
            short8 bkv = lds_read_frag(kvp, nt * 16 + (lane & 15), ks * 32 + (lane >> 4) * 8);
            acc[nt] = __builtin_amdgcn_mfma_f32_16x16x32_bf16(ap, bv,  acc[nt], 0, 0, 0);
            acc[nt] = __builtin_amdgcn_mfma_f32_16x16x32_bf16(aq, bkv, acc[nt], 0, 0, 0);
        }
    }
    // denominator lives in col 64 -> lanes with (lane&15)==0 of N-tile 4
    float dinv[4];
    #pragma unroll
    for (int t = 0; t < 4; ++t) {
        const float d = __shfl(acc[4][t], lane & 48, 64);
        dinv[t] = 1.f / (d + 1e-6f);
    }
    #pragma unroll
    for (int nt = 0; nt < 4; ++nt)
        #pragma unroll
        for (int t = 0; t < 4; ++t) {
            const int r = r0 + (lane >> 4) * 4 + t, j = nt * 16 + (lane & 15);
            attnb[(size_t)(s0 + r) * DIM + (size_t)h * HD + j] = f2bf(acc[nt][t] * dinv[t]);
        }
}

extern "C" void kernel_launch(void* const* d_in, const int* in_sizes, int n_in,
                              void* d_out, int out_size, void* d_ws, size_t ws_size,
                              hipStream_t stream)
{
    const float* x     = (const float*)d_in[0];
    const float* W_qkv = (const float*)d_in[2];
    const float* W_out = (const float*)d_in[3];
    float* out = (float*)d_out;

    char* ws = (char*)d_ws;
    size_t off = 0;
    unsigned short* qkvb = (unsigned short*)(ws + off); off += (size_t)SEQ * 3 * DIM * 2;       // 12.6 MB
    unsigned short* xb   = (unsigned short*)(ws + off); off += (size_t)SEQ * DIM * 2;           //  4.2 MB
    float*          kvs  = (float*)         (ws + off); off += (size_t)NH * NCK * KVR * 64 * 4; //  8.5 MB
    unsigned short* kvpb = (unsigned short*)(ws + off); off += (size_t)NH * NCK * KVR * 64 * 2; //  4.3 MB
    unsigned short* wqt  = (unsigned short*)(ws + off); off += (size_t)3 * DIM * DIM * 2;       //  6.3 MB
    unsigned short* wot  = (unsigned short*)(ws + off); off += (size_t)DIM * DIM * 2;           //  2.1 MB
    // attnb aliases xb: qkv-GEMM finishes reading xb before attn_chunk writes (stream-ordered)
    unsigned short* attnb = xb;

    dim3 blk(256);

    to_bf16_vec<<<dim3(SEQ * DIM / 1024), blk, 0, stream>>>(x, xb, SEQ * DIM);
    transpose_to_bf16<<<dim3(3 * DIM / 32, DIM / 32), blk, 0, stream>>>(W_qkv, wqt, DIM, 3 * DIM);
    transpose_to_bf16<<<dim3(DIM / 32, DIM / 32), blk, 0, stream>>>(W_out, wot, DIM, DIM);

    gemm_bf16<1><<<dim3(3 * DIM / 128, SEQ / 128), blk, 0, stream>>>(
        xb, wqt, qkvb, SEQ, 3 * DIM, DIM);

    chunk_kv<<<dim3(NCK, NH), blk, 0, stream>>>(qkvb, kvs);
    scan_kv<<<dim3((NH * KVR * 64 + 255) / 256), blk, 0, stream>>>(kvs, kvpb);
    attn_chunk<<<dim3(NCK, NH), blk, 0, stream>>>(qkvb, kvpb, attnb);

    gemm_bf16<0><<<dim3(DIM / 128, SEQ / 128), blk, 0, stream>>>(
        attnb, wot, out, SEQ, DIM, DIM);
}

// Round 4
// 72.751 us; speedup vs baseline: 5.7763x; 1.1155x over previous
//
#include <hip/hip_runtime.h>
#include <cstddef>
#include <cstdint>

#define SEQ 2048
#define DIM 1024
#define NH 16
#define HD 64
#define CK 64
#define NCK (SEQ / CK)     // 32 chunks
#define KVR 65             // KV^T rows incl. ksum row
#define KVRP 80            // padded to 5 MFMA tiles

typedef __attribute__((ext_vector_type(8))) short short8;            // 8 bf16
typedef __attribute__((ext_vector_type(8))) unsigned short ushort8;  // 8 raw bf16
typedef __attribute__((ext_vector_type(4))) float fx4;

__device__ __forceinline__ float phi_fn(float x) {
    return x > 0.f ? x + 1.f : __expf(x);   // elu(x)+1
}
__device__ __forceinline__ float bf2f(unsigned short u) {
    return __uint_as_float((unsigned int)u << 16);
}
__device__ __forceinline__ unsigned short f2bf(float f) {
    unsigned int u = __float_as_uint(f);
    unsigned int r = (u + 0x7FFFu + ((u >> 16) & 1u)) >> 16;   // RNE
    return (unsigned short)r;
}

// ---- swizzled LDS helpers: row stride 64 ushort (128 B); byte ^= (row&7)<<4 ----
__device__ __forceinline__ void lds_write16(unsigned short* base, int row, int col, short8 v) {
    int byte = row * 128 + col * 2; byte ^= (row & 7) << 4;
    *(short8*)((char*)base + byte) = v;
}
__device__ __forceinline__ void lds_write2(unsigned short* base, int row, int col, unsigned short v) {
    int byte = row * 128 + col * 2; byte ^= (row & 7) << 4;
    *(unsigned short*)((char*)base + byte) = v;
}
__device__ __forceinline__ short8 lds_read_frag(const unsigned short* base, int row, int kcol) {
    int byte = row * 128 + kcol * 2; byte ^= (row & 7) << 4;
    return *(const short8*)((const char*)base + byte);
}

template<int N> __device__ __forceinline__ void waitv() {
    if constexpr (N == 12)     asm volatile("s_waitcnt vmcnt(12)" ::: "memory");
    else if constexpr (N == 8) asm volatile("s_waitcnt vmcnt(8)"  ::: "memory");
    else if constexpr (N == 6) asm volatile("s_waitcnt vmcnt(6)"  ::: "memory");
    else if constexpr (N == 4) asm volatile("s_waitcnt vmcnt(4)"  ::: "memory");
    else                       asm volatile("s_waitcnt vmcnt(0)"  ::: "memory");
}

// ---------------- fp32 -> bf16 elementwise ----------------
__global__ __launch_bounds__(256)
void to_bf16_vec(const float* __restrict__ in, unsigned short* __restrict__ out, int n)
{
    const int i = (blockIdx.x * 256 + threadIdx.x) * 4;
    if (i >= n) return;
    float4 v = *(const float4*)&in[i];
    ushort4 o;
    o.x = f2bf(v.x); o.y = f2bf(v.y); o.z = f2bf(v.z); o.w = f2bf(v.w);
    *(ushort4*)&out[i] = o;
}

// ---------------- W (KxN f32) -> WT (NxK bf16) ----------------
__global__ __launch_bounds__(256)
void transpose_to_bf16(const float* __restrict__ W, unsigned short* __restrict__ WT,
                       int K, int N)
{
    __shared__ float t[32][33];
    const int kb = blockIdx.y * 32, nb = blockIdx.x * 32;
    const int c = threadIdx.x & 31, r0 = threadIdx.x >> 5;
    #pragma unroll
    for (int i = 0; i < 4; ++i) {
        const int r = r0 + i * 8;
        t[r][c] = W[(size_t)(kb + r) * N + nb + c];
    }
    __syncthreads();
    #pragma unroll
    for (int i = 0; i < 4; ++i) {
        const int r = r0 + i * 8;
        WT[(size_t)(nb + r) * K + kb + c] = f2bf(t[c][r]);
    }
}

// ============ 3-deep pipelined bf16 MFMA GEMM: C(MxN)=A(MxK)@BT(NxK)^T ============
// BM=128, BK=64, BN template (256 or 128). 512 threads = 8 waves (2M x 4N).
// Raw s_barrier + counted vmcnt: loads for tiles t+2,t+3 stay in flight across
// barriers (T3+T4); setprio around MFMA cluster (T5); XOR-swizzled LDS via
// pre-swizzled global source (T2, both-sides rule #21).
template<int BN, int OUT_BF16>
__global__ __launch_bounds__(512)
void gemm_pipe(const unsigned short* __restrict__ A,
               const unsigned short* __restrict__ BT,
               void* __restrict__ Cout, int M, int N, int K)
{
    constexpr int ATILE  = 128 * 64;              // ushorts
    constexpr int BTILE  = BN * 64;
    constexpr int ALOADS = 2;                     // 16 KB / (512 thr * 16 B)
    constexpr int BLOADS = (BTILE * 2) / 8192;    // 4 (BN=256) or 2 (BN=128)
    constexpr int LOADS  = ALOADS + BLOADS;       // 6 or 4
    constexpr int NFRAG  = BN / 64;               // per-wave N frags: 4 or 2

    __shared__ unsigned short As[3][ATILE];
    __shared__ unsigned short Bs[3][BTILE];

    const int tid = threadIdx.x, lane = tid & 63, wave = tid >> 6;
    const int wm = (wave >> 2) * 64;              // 2 wave-rows of 64
    const int wn = (wave & 3) * (BN / 4);         // 4 wave-cols
    const int m0 = blockIdx.y * 128, n0 = blockIdx.x * BN;
    const unsigned short* Abase = A + (size_t)m0 * K;
    const unsigned short* Bbase = BT + (size_t)n0 * K;
    const int nt = K >> 6;
    const int fr = lane & 15, fk = (lane >> 4) * 8;

    fx4 acc[4][NFRAG] = {};

    auto STAGE = [&](int slot, int t) {
        const int k0 = t << 6;
        #pragma unroll
        for (int q = 0; q < ALOADS; ++q) {
            const int L = q * 8192 + wave * 1024 + lane * 16;   // linear dest byte
            const int row = L >> 7;
            const int srcb = L ^ ((row & 7) << 4);              // inverse swizzle
            const unsigned short* g = Abase + (size_t)row * K + k0 + ((srcb & 127) >> 1);
            __builtin_amdgcn_global_load_lds(
                (const __attribute__((address_space(1))) void*)g,
                (__attribute__((address_space(3))) void*)((char*)&As[slot][0] + q * 8192 + wave * 1024),
                16, 0, 0);
        }
        #pragma unroll
        for (int q = 0; q < BLOADS; ++q) {
            const int L = q * 8192 + wave * 1024 + lane * 16;
            const int row = L >> 7;
            const int srcb = L ^ ((row & 7) << 4);
            const unsigned short* g = Bbase + (size_t)row * K + k0 + ((srcb & 127) >> 1);
            __builtin_amdgcn_global_load_lds(
                (const __attribute__((address_space(1))) void*)g,
                (__attribute__((address_space(3))) void*)((char*)&Bs[slot][0] + q * 8192 + wave * 1024),
                16, 0, 0);
        }
    };

    // prologue: 3 tiles in flight, wait for tile 0
    STAGE(0, 0); STAGE(1, 1); STAGE(2, 2);
    waitv<2 * LOADS>();
    __builtin_amdgcn_s_barrier();

    int cur = 0;
    for (int t = 0; t < nt; ++t) {
        short8 a0[4], a1[4], b0[NFRAG], b1[NFRAG];
        #pragma unroll
        for (int i = 0; i < 4; ++i) {
            a0[i] = lds_read_frag(&As[cur][0], wm + i * 16 + fr, fk);
            a1[i] = lds_read_frag(&As[cur][0], wm + i * 16 + fr, 32 + fk);
        }
        #pragma unroll
        for (int j = 0; j < NFRAG; ++j) {
            b0[j] = lds_read_frag(&Bs[cur][0], wn + j * 16 + fr, fk);
            b1[j] = lds_read_frag(&Bs[cur][0], wn + j * 16 + fr, 32 + fk);
        }
        asm volatile("s_waitcnt lgkmcnt(0)" ::: "memory");
        __builtin_amdgcn_sched_barrier(0);
        __builtin_amdgcn_s_barrier();                 // all waves done reading slot cur

        const bool refill = (t + 3 < nt);
        if (refill) STAGE(cur, t + 3);                // overwrite freed slot

        __builtin_amdgcn_s_setprio(1);
        #pragma unroll
        for (int i = 0; i < 4; ++i)
            #pragma unroll
            for (int j = 0; j < NFRAG; ++j)
                acc[i][j] = __builtin_amdgcn_mfma_f32_16x16x32_bf16(a0[i], b0[j], acc[i][j], 0, 0, 0);
        #pragma unroll
        for (int i = 0; i < 4; ++i)
            #pragma unroll
            for (int j = 0; j < NFRAG; ++j)
                acc[i][j] = __builtin_amdgcn_mfma_f32_16x16x32_bf16(a1[i], b1[j], acc[i][j], 0, 0, 0);
        __builtin_amdgcn_s_setprio(0);

        // guarantee tile t+1 landed; keep t+2 (,t+3) in flight
        if (refill)            waitv<2 * LOADS>();
        else if (t == nt - 3)  waitv<LOADS>();
        else                   waitv<0>();
        __builtin_amdgcn_s_barrier();
        cur = (cur == 2) ? 0 : cur + 1;
    }

    // C/D layout: col = lane&15, row = (lane>>4)*4 + reg
    const int cr = (lane >> 4) * 4, cc = lane & 15;
    #pragma unroll
    for (int i = 0; i < 4; ++i)
        #pragma unroll
        for (int j = 0; j < NFRAG; ++j) {
            const int m = m0 + wm + i * 16 + cr;
            const int n = n0 + wn + j * 16 + cc;
            #pragma unroll
            for (int r = 0; r < 4; ++r) {
                const float v = acc[i][j][r];
                if (OUT_BF16)
                    ((unsigned short*)Cout)[(size_t)(m + r) * N + n] = f2bf(v);
                else
                    ((float*)Cout)[(size_t)(m + r) * N + n] = v;
            }
        }
}

// ---------------- Phase A: per-(head,chunk) KV^T sums via MFMA ----------------
__global__ __launch_bounds__(256)
void chunk_kv(const unsigned short* __restrict__ qkv, float* __restrict__ kvs)
{
    const int c = blockIdx.x, h = blockIdx.y;
    __shared__ unsigned short kT[64 * 64];    // [i=d][s], swizzled
    __shared__ unsigned short vT[KVRP * 64];  // [j][s], row64=ones, 65-79=0
    const int tid = threadIdx.x, lane = tid & 63, wave = tid >> 6;
    const int s0 = c * CK;

    #pragma unroll
    for (int part = 0; part < 2; ++part) {
        const int s = (tid >> 3) + part * 32;
        const int d0 = (tid & 7) * 8;
        const size_t base = (size_t)(s0 + s) * (3 * DIM) + (size_t)h * HD + d0;
        ushort8 kk = *(const ushort8*)&qkv[base + DIM];
        ushort8 vv = *(const ushort8*)&qkv[base + 2 * DIM];
        #pragma unroll
        for (int u = 0; u < 8; ++u) {
            lds_write2(kT, d0 + u, s, f2bf(phi_fn(bf2f(kk[u]))));
            lds_write2(vT, d0 + u, s, vv[u]);
        }
    }
    if (tid < 64) lds_write2(vT, 64, tid, 0x3F80);   // bf16 1.0
    for (int idx = tid; idx < 15 * 64; idx += 256)
        lds_write2(vT, 65 + (idx >> 6), idx & 63, 0);
    __syncthreads();

    fx4 acc[5] = {};
    #pragma unroll
    for (int ks = 0; ks < 2; ++ks) {
        short8 b = lds_read_frag(kT, wave * 16 + (lane & 15), ks * 32 + (lane >> 4) * 8);
        #pragma unroll
        for (int mt = 0; mt < 5; ++mt) {
            short8 a = lds_read_frag(vT, mt * 16 + (lane & 15), ks * 32 + (lane >> 4) * 8);
            acc[mt] = __builtin_amdgcn_mfma_f32_16x16x32_bf16(a, b, acc[mt], 0, 0, 0);
        }
    }
    float* dst = kvs + (size_t)(h * NCK + c) * KVR * 64;
    const int i = wave * 16 + (lane & 15);
    #pragma unroll
    for (int mt = 0; mt < 5; ++mt)
        #pragma unroll
        for (int t = 0; t < 4; ++t) {
            const int j = mt * 16 + (lane >> 4) * 4 + t;
            if (j < KVR) dst[(size_t)j * 64 + i] = acc[mt][t];
        }
}

// ---------------- Phase B: exclusive prefix scan (ILP loads), bf16 out -------
__global__ __launch_bounds__(256)
void scan_kv(const float* __restrict__ kvs, unsigned short* __restrict__ kvpb)
{
    const int e = blockIdx.x * 256 + threadIdx.x;
    if (e >= NH * KVR * 64) return;
    const int h = e / (KVR * 64), off = e % (KVR * 64);
    const float* src = kvs + (size_t)h * NCK * KVR * 64 + off;
    unsigned short* dst = kvpb + (size_t)h * NCK * KVR * 64 + off;
    float v[NCK];
    #pragma unroll
    for (int c2 = 0; c2 < NCK; ++c2) v[c2] = src[(size_t)c2 * KVR * 64];
    float run = 0.f;
    #pragma unroll
    for (int c2 = 0; c2 < NCK; ++c2) {
        dst[(size_t)c2 * KVR * 64] = f2bf(run);
        run += v[c2];
    }
}

// ---------------- Phase C: per-(head,chunk) outputs via MFMA ----------------
__global__ __launch_bounds__(256)
void attn_chunk(const unsigned short* __restrict__ qkv,
                const unsigned short* __restrict__ kvpb,
                unsigned short* __restrict__ attnb)
{
    const int c = blockIdx.x, h = blockIdx.y;
    __shared__ unsigned short q_s[64 * 64];   // phi_q [r][d]
    __shared__ unsigned short k_s[64 * 64];   // phi_k [s][d]
    __shared__ unsigned short p_s[64 * 64];   // masked P bf16 [r][s]
    __shared__ unsigned short vT[KVRP * 64];  // V^T [j][s], row64=ones
    __shared__ unsigned short kvp[KVRP * 64]; // KVp^T_aug [j][d], row64=ksp
    const int tid = threadIdx.x, lane = tid & 63, wave = tid >> 6;
    const int s0 = c * CK;

    #pragma unroll
    for (int part = 0; part < 2; ++part) {
        const int s = (tid >> 3) + part * 32;
        const int d0 = (tid & 7) * 8;
        const size_t base = (size_t)(s0 + s) * (3 * DIM) + (size_t)h * HD + d0;
        ushort8 qq = *(const ushort8*)&qkv[base];
        ushort8 kk = *(const ushort8*)&qkv[base + DIM];
        ushort8 vv = *(const ushort8*)&qkv[base + 2 * DIM];
        short8 qo, ko;
        #pragma unroll
        for (int u = 0; u < 8; ++u) {
            qo[u] = (short)f2bf(phi_fn(bf2f(qq[u])));
            ko[u] = (short)f2bf(phi_fn(bf2f(kk[u])));
        }
        lds_write16(q_s, s, d0, qo);
        lds_write16(k_s, s, d0, ko);
        #pragma unroll
        for (int u = 0; u < 8; ++u)
            lds_write2(vT, d0 + u, s, vv[u]);
    }
    const unsigned short* kv_src = kvpb + (size_t)(h * NCK + c) * KVR * 64;
    for (int idx = tid * 8; idx < KVR * 64; idx += 2048) {
        ushort8 kv8 = *(const ushort8*)&kv_src[idx];
        short8 kv8s;
        #pragma unroll
        for (int u = 0; u < 8; ++u) kv8s[u] = (short)kv8[u];
        lds_write16(kvp, idx >> 6, idx & 63, kv8s);
    }
    if (tid < 64) lds_write2(vT, 64, tid, 0x3F80);
    for (int idx = tid; idx < 15 * 64; idx += 256) {
        lds_write2(vT, 65 + (idx >> 6), idx & 63, 0);
        lds_write2(kvp, 65 + (idx >> 6), idx & 63, 0);
    }
    __syncthreads();

    const int r0 = wave * 16;
    fx4 accp[4] = {};
    #pragma unroll
    for (int ks = 0; ks < 2; ++ks) {
        short8 aq = lds_read_frag(q_s, r0 + (lane & 15), ks * 32 + (lane >> 4) * 8);
        #pragma unroll
        for (int nt = 0; nt < 4; ++nt) {
            short8 bk = lds_read_frag(k_s, nt * 16 + (lane & 15), ks * 32 + (lane >> 4) * 8);
            accp[nt] = __builtin_amdgcn_mfma_f32_16x16x32_bf16(aq, bk, accp[nt], 0, 0, 0);
        }
    }
    #pragma unroll
    for (int nt = 0; nt < 4; ++nt)
        #pragma unroll
        for (int t = 0; t < 4; ++t) {
            const int r = r0 + (lane >> 4) * 4 + t, sc = nt * 16 + (lane & 15);
            lds_write2(p_s, r, sc, (sc <= r) ? f2bf(accp[nt][t]) : (unsigned short)0);
        }
    __syncthreads();

    fx4 acc[5] = {};
    #pragma unroll
    for (int ks = 0; ks < 2; ++ks) {
        short8 ap = lds_read_frag(p_s, r0 + (lane & 15), ks * 32 + (lane >> 4) * 8);
        short8 aq = lds_read_frag(q_s, r0 + (lane & 15), ks * 32 + (lane >> 4) * 8);
        #pragma unroll
        for (int nt = 0; nt < 5; ++nt) {
            short8 bv  = lds_read_frag(vT,  nt * 16 + (lane & 15), ks * 32 + (lane >> 4) * 8);
            short8 bkv = lds_read_frag(kvp, nt * 16 + (lane & 15), ks * 32 + (lane >> 4) * 8);
            acc[nt] = __builtin_amdgcn_mfma_f32_16x16x32_bf16(ap, bv,  acc[nt], 0, 0, 0);
            acc[nt] = __builtin_amdgcn_mfma_f32_16x16x32_bf16(aq, bkv, acc[nt], 0, 0, 0);
        }
    }
    float dinv[4];
    #pragma unroll
    for (int t = 0; t < 4; ++t) {
        const float d = __shfl(acc[4][t], lane & 48, 64);
        dinv[t] = 1.f / (d + 1e-6f);
    }
    #pragma unroll
    for (int nt = 0; nt < 4; ++nt)
        #pragma unroll
        for (int t = 0; t < 4; ++t) {
            const int r = r0 + (lane >> 4) * 4 + t, j = nt * 16 + (lane & 15);
            attnb[(size_t)(s0 + r) * DIM + (size_t)h * HD + j] = f2bf(acc[nt][t] * dinv[t]);
        }
}

extern "C" void kernel_launch(void* const* d_in, const int* in_sizes, int n_in,
                              void* d_out, int out_size, void* d_ws, size_t ws_size,
                              hipStream_t stream)
{
    const float* x     = (const float*)d_in[0];
    const float* W_qkv = (const float*)d_in[2];
    const float* W_out = (const float*)d_in[3];
    float* out = (float*)d_out;

    char* ws = (char*)d_ws;
    size_t off = 0;
    unsigned short* qkvb = (unsigned short*)(ws + off); off += (size_t)SEQ * 3 * DIM * 2;       // 12.6 MB
    unsigned short* xb   = (unsigned short*)(ws + off); off += (size_t)SEQ * DIM * 2;           //  4.2 MB
    float*          kvs  = (float*)         (ws + off); off += (size_t)NH * NCK * KVR * 64 * 4; //  8.5 MB
    unsigned short* kvpb = (unsigned short*)(ws + off); off += (size_t)NH * NCK * KVR * 64 * 2; //  4.3 MB
    unsigned short* wqt  = (unsigned short*)(ws + off); off += (size_t)3 * DIM * DIM * 2;       //  6.3 MB
    unsigned short* wot  = (unsigned short*)(ws + off); off += (size_t)DIM * DIM * 2;           //  2.1 MB
    unsigned short* attnb = xb;   // alias: qkv-GEMM finishes reading xb first (stream order)

    dim3 blk(256);

    to_bf16_vec<<<dim3(SEQ * DIM / 1024), blk, 0, stream>>>(x, xb, SEQ * DIM);
    transpose_to_bf16<<<dim3(3 * DIM / 32, DIM / 32), blk, 0, stream>>>(W_qkv, wqt, DIM, 3 * DIM);
    transpose_to_bf16<<<dim3(DIM / 32, DIM / 32), blk, 0, stream>>>(W_out, wot, DIM, DIM);

    // qkv = x @ W_qkv : M=2048, N=3072, K=1024 -> 12x16 = 192 blocks
    gemm_pipe<256, 1><<<dim3(3 * DIM / 256, SEQ / 128), dim3(512), 0, stream>>>(
        xb, wqt, qkvb, SEQ, 3 * DIM, DIM);

    chunk_kv<<<dim3(NCK, NH), blk, 0, stream>>>(qkvb, kvs);
    scan_kv<<<dim3((NH * KVR * 64 + 255) / 256), blk, 0, stream>>>(kvs, kvpb);
    attn_chunk<<<dim3(NCK, NH), blk, 0, stream>>>(qkvb, kvpb, attnb);

    // out = attn @ W_out : M=2048, N=1024, K=1024 -> 8x16 = 128 blocks
    gemm_pipe<128, 0><<<dim3(DIM / 128, SEQ / 128), dim3(512), 0, stream>>>(
        attnb, wot, out, SEQ, DIM, DIM);
}

// Round 5
// 66.404 us; speedup vs baseline: 6.3284x; 1.0956x over previous
//
#include <hip/hip_runtime.h>
#include <cstddef>
#include <cstdint>

#define SEQ 2048
#define DIM 1024
#define NH 16
#define HD 64
#define CK 64
#define NCK (SEQ / CK)     // 32 chunks
#define KVR 65             // KV^T rows incl. ksum row
#define KVRP 80            // padded to 5 MFMA tiles

typedef __attribute__((ext_vector_type(8))) short short8;            // 8 bf16
typedef __attribute__((ext_vector_type(8))) unsigned short ushort8;  // 8 raw bf16
typedef __attribute__((ext_vector_type(4))) float fx4;

__device__ __forceinline__ float phi_fn(float x) {
    return x > 0.f ? x + 1.f : __expf(x);   // elu(x)+1
}
__device__ __forceinline__ float bf2f(unsigned short u) {
    return __uint_as_float((unsigned int)u << 16);
}
__device__ __forceinline__ unsigned short f2bf(float f) {
    unsigned int u = __float_as_uint(f);
    unsigned int r = (u + 0x7FFFu + ((u >> 16) & 1u)) >> 16;   // RNE
    return (unsigned short)r;
}

// ---- swizzled LDS helpers: row stride 64 ushort (128 B); byte ^= (row&7)<<4 ----
__device__ __forceinline__ void lds_write16(unsigned short* base, int row, int col, short8 v) {
    int byte = row * 128 + col * 2; byte ^= (row & 7) << 4;
    *(short8*)((char*)base + byte) = v;
}
__device__ __forceinline__ void lds_write2(unsigned short* base, int row, int col, unsigned short v) {
    int byte = row * 128 + col * 2; byte ^= (row & 7) << 4;
    *(unsigned short*)((char*)base + byte) = v;
}
__device__ __forceinline__ short8 lds_read_frag(const unsigned short* base, int row, int kcol) {
    int byte = row * 128 + kcol * 2; byte ^= (row & 7) << 4;
    return *(const short8*)((const char*)base + byte);
}

template<int N> __device__ __forceinline__ void waitv() {
    if constexpr (N == 0)       asm volatile("s_waitcnt vmcnt(0)"  ::: "memory");
    else if constexpr (N == 4)  asm volatile("s_waitcnt vmcnt(4)"  ::: "memory");
    else if constexpr (N == 5)  asm volatile("s_waitcnt vmcnt(5)"  ::: "memory");
    else if constexpr (N == 6)  asm volatile("s_waitcnt vmcnt(6)"  ::: "memory");
    else if constexpr (N == 8)  asm volatile("s_waitcnt vmcnt(8)"  ::: "memory");
    else if constexpr (N == 10) asm volatile("s_waitcnt vmcnt(10)" ::: "memory");
    else if constexpr (N == 12) asm volatile("s_waitcnt vmcnt(12)" ::: "memory");
    else                        asm volatile("s_waitcnt vmcnt(0)"  ::: "memory");
}

// ---------------- fp32 -> bf16 elementwise ----------------
__global__ __launch_bounds__(256)
void to_bf16_vec(const float* __restrict__ in, unsigned short* __restrict__ out, int n)
{
    const int i = (blockIdx.x * 256 + threadIdx.x) * 4;
    if (i >= n) return;
    float4 v = *(const float4*)&in[i];
    ushort4 o;
    o.x = f2bf(v.x); o.y = f2bf(v.y); o.z = f2bf(v.z); o.w = f2bf(v.w);
    *(ushort4*)&out[i] = o;
}

// -------- fused: W_qkv (1024x3072) and W_out (1024x1024) -> bf16 transposed --------
__global__ __launch_bounds__(256)
void transpose2_to_bf16(const float* __restrict__ W1, unsigned short* __restrict__ WT1,
                        const float* __restrict__ W2, unsigned short* __restrict__ WT2)
{
    __shared__ float t[32][33];
    const float* W; unsigned short* WT; int N, kb, nb;
    if (blockIdx.x < 96 * 32) {
        W = W1; WT = WT1; N = 3 * DIM;
        nb = (blockIdx.x % 96) * 32; kb = (blockIdx.x / 96) * 32;
    } else {
        const int b = blockIdx.x - 96 * 32;
        W = W2; WT = WT2; N = DIM;
        nb = (b % 32) * 32; kb = (b / 32) * 32;
    }
    const int c = threadIdx.x & 31, r0 = threadIdx.x >> 5;
    #pragma unroll
    for (int i = 0; i < 4; ++i) {
        const int r = r0 + i * 8;
        t[r][c] = W[(size_t)(kb + r) * N + nb + c];
    }
    __syncthreads();
    #pragma unroll
    for (int i = 0; i < 4; ++i) {
        const int r = r0 + i * 8;
        WT[(size_t)(nb + r) * DIM + kb + c] = f2bf(t[c][r]);
    }
}

// ============ 3-deep pipelined bf16 MFMA GEMM: C(MxN)=A(MxK)@BT(NxK)^T ============
// BM = WAVES_M*64 = 128. BN = WAVES_N*NFRAG*16. THREADS = WAVES_M*WAVES_N*64.
// Counted vmcnt keeps 2 tiles in flight across raw barriers (T3+T4); setprio (T5);
// XOR-swizzled LDS via pre-swizzled global source (T2); XCD swizzle (T1).
template<int WAVES_M, int WAVES_N, int NFRAG, int OUT_BF16>
__global__ __launch_bounds__(WAVES_M * WAVES_N * 64)
void gemm_pipe(const unsigned short* __restrict__ A,
               const unsigned short* __restrict__ BT,
               void* __restrict__ Cout, int M, int N, int K)
{
    constexpr int BN      = WAVES_N * NFRAG * 16;
    constexpr int THREADS = WAVES_M * WAVES_N * 64;
    constexpr int CHUNK   = THREADS * 16;              // bytes per load-op
    constexpr int ALOADS  = (128 * 64 * 2) / CHUNK;
    constexpr int BLOADS  = (BN * 64 * 2) / CHUNK;
    constexpr int LOADS   = ALOADS + BLOADS;

    __shared__ unsigned short As[3][128 * 64];
    __shared__ unsigned short Bs[3][BN * 64];

    const int tid = threadIdx.x, lane = tid & 63, wave = tid >> 6;
    const int wm = (wave / WAVES_N) * 64;
    const int wn = (wave % WAVES_N) * (NFRAG * 16);

    // XCD-aware block swizzle (nwg divisible by 8; column-major work chunks)
    int wg = blockIdx.y * gridDim.x + blockIdx.x;
    const int cpx = (gridDim.x * gridDim.y) >> 3;
    wg = (wg & 7) * cpx + (wg >> 3);
    const int bx = wg / gridDim.y;
    const int by = wg % gridDim.y;

    const int m0 = by * 128, n0 = bx * BN;
    const unsigned short* Abase = A + (size_t)m0 * K;
    const unsigned short* Bbase = BT + (size_t)n0 * K;
    const int nt = K >> 6;
    const int fr = lane & 15, fk = (lane >> 4) * 8;

    fx4 acc[4][NFRAG] = {};

    auto STAGE = [&](int slot, int t) {
        const int k0 = t << 6;
        #pragma unroll
        for (int q = 0; q < ALOADS; ++q) {
            const int L = q * CHUNK + tid * 16;                 // linear dest byte
            const int row = L >> 7;
            const int srcb = L ^ ((row & 7) << 4);              // inverse swizzle
            const unsigned short* g = Abase + (size_t)row * K + k0 + ((srcb & 127) >> 1);
            __builtin_amdgcn_global_load_lds(
                (const __attribute__((address_space(1))) void*)g,
                (__attribute__((address_space(3))) void*)((char*)&As[slot][0] + q * CHUNK + wave * 1024),
                16, 0, 0);
        }
        #pragma unroll
        for (int q = 0; q < BLOADS; ++q) {
            const int L = q * CHUNK + tid * 16;
            const int row = L >> 7;
            const int srcb = L ^ ((row & 7) << 4);
            const unsigned short* g = Bbase + (size_t)row * K + k0 + ((srcb & 127) >> 1);
            __builtin_amdgcn_global_load_lds(
                (const __attribute__((address_space(1))) void*)g,
                (__attribute__((address_space(3))) void*)((char*)&Bs[slot][0] + q * CHUNK + wave * 1024),
                16, 0, 0);
        }
    };

    // prologue: 3 tiles in flight, wait for tile 0
    STAGE(0, 0); STAGE(1, 1); STAGE(2, 2);
    waitv<2 * LOADS>();
    __builtin_amdgcn_s_barrier();

    int cur = 0;
    for (int t = 0; t < nt; ++t) {
        short8 a0[4], a1[4], b0[NFRAG], b1[NFRAG];
        #pragma unroll
        for (int i = 0; i < 4; ++i) {
            a0[i] = lds_read_frag(&As[cur][0], wm + i * 16 + fr, fk);
            a1[i] = lds_read_frag(&As[cur][0], wm + i * 16 + fr, 32 + fk);
        }
        #pragma unroll
        for (int j = 0; j < NFRAG; ++j) {
            b0[j] = lds_read_frag(&Bs[cur][0], wn + j * 16 + fr, fk);
            b1[j] = lds_read_frag(&Bs[cur][0], wn + j * 16 + fr, 32 + fk);
        }
        asm volatile("s_waitcnt lgkmcnt(0)" ::: "memory");
        __builtin_amdgcn_sched_barrier(0);
        __builtin_amdgcn_s_barrier();                 // all waves done reading slot cur

        const bool refill = (t + 3 < nt);
        if (refill) STAGE(cur, t + 3);                // overwrite freed slot

        __builtin_amdgcn_s_setprio(1);
        #pragma unroll
        for (int i = 0; i < 4; ++i)
            #pragma unroll
            for (int j = 0; j < NFRAG; ++j)
                acc[i][j] = __builtin_amdgcn_mfma_f32_16x16x32_bf16(a0[i], b0[j], acc[i][j], 0, 0, 0);
        #pragma unroll
        for (int i = 0; i < 4; ++i)
            #pragma unroll
            for (int j = 0; j < NFRAG; ++j)
                acc[i][j] = __builtin_amdgcn_mfma_f32_16x16x32_bf16(a1[i], b1[j], acc[i][j], 0, 0, 0);
        __builtin_amdgcn_s_setprio(0);

        // guarantee tile t+1 landed; keep t+2 (,t+3) in flight
        if (refill)            waitv<2 * LOADS>();
        else if (t == nt - 3)  waitv<LOADS>();
        else                   waitv<0>();
        __builtin_amdgcn_s_barrier();
        cur = (cur == 2) ? 0 : cur + 1;
    }

    // C/D layout: col = lane&15, row = (lane>>4)*4 + reg
    const int cr = (lane >> 4) * 4, cc = lane & 15;
    #pragma unroll
    for (int i = 0; i < 4; ++i)
        #pragma unroll
        for (int j = 0; j < NFRAG; ++j) {
            const int m = m0 + wm + i * 16 + cr;
            const int n = n0 + wn + j * 16 + cc;
            #pragma unroll
            for (int r = 0; r < 4; ++r) {
                const float v = acc[i][j][r];
                if (OUT_BF16)
                    ((unsigned short*)Cout)[(size_t)(m + r) * N + n] = f2bf(v);
                else
                    ((float*)Cout)[(size_t)(m + r) * N + n] = v;
            }
        }
}

// ---------------- Phase A: per-(head,chunk) KV^T sums via MFMA ----------------
__global__ __launch_bounds__(256)
void chunk_kv(const unsigned short* __restrict__ qkv, float* __restrict__ kvs)
{
    const int c = blockIdx.x, h = blockIdx.y;
    __shared__ unsigned short kT[64 * 64];    // [i=d][s], swizzled
    __shared__ unsigned short vT[KVRP * 64];  // [j][s], row64=ones, 65-79=0
    const int tid = threadIdx.x, lane = tid & 63, wave = tid >> 6;
    const int s0 = c * CK;

    #pragma unroll
    for (int part = 0; part < 2; ++part) {
        const int s = (tid >> 3) + part * 32;
        const int d0 = (tid & 7) * 8;
        const size_t base = (size_t)(s0 + s) * (3 * DIM) + (size_t)h * HD + d0;
        ushort8 kk = *(const ushort8*)&qkv[base + DIM];
        ushort8 vv = *(const ushort8*)&qkv[base + 2 * DIM];
        #pragma unroll
        for (int u = 0; u < 8; ++u) {
            lds_write2(kT, d0 + u, s, f2bf(phi_fn(bf2f(kk[u]))));
            lds_write2(vT, d0 + u, s, vv[u]);
        }
    }
    if (tid < 64) lds_write2(vT, 64, tid, 0x3F80);   // bf16 1.0
    for (int idx = tid; idx < 15 * 64; idx += 256)
        lds_write2(vT, 65 + (idx >> 6), idx & 63, 0);
    __syncthreads();

    fx4 acc[5] = {};
    #pragma unroll
    for (int ks = 0; ks < 2; ++ks) {
        short8 b = lds_read_frag(kT, wave * 16 + (lane & 15), ks * 32 + (lane >> 4) * 8);
        #pragma unroll
        for (int mt = 0; mt < 5; ++mt) {
            short8 a = lds_read_frag(vT, mt * 16 + (lane & 15), ks * 32 + (lane >> 4) * 8);
            acc[mt] = __builtin_amdgcn_mfma_f32_16x16x32_bf16(a, b, acc[mt], 0, 0, 0);
        }
    }
    float* dst = kvs + (size_t)(h * NCK + c) * KVR * 64;
    const int i = wave * 16 + (lane & 15);
    #pragma unroll
    for (int mt = 0; mt < 5; ++mt)
        #pragma unroll
        for (int t = 0; t < 4; ++t) {
            const int j = mt * 16 + (lane >> 4) * 4 + t;
            if (j < KVR) dst[(size_t)j * 64 + i] = acc[mt][t];
        }
}

// ---------------- Phase B: exclusive prefix scan (ILP loads), bf16 out -------
__global__ __launch_bounds__(256)
void scan_kv(const float* __restrict__ kvs, unsigned short* __restrict__ kvpb)
{
    const int e = blockIdx.x * 256 + threadIdx.x;
    if (e >= NH * KVR * 64) return;
    const int h = e / (KVR * 64), off = e % (KVR * 64);
    const float* src = kvs + (size_t)h * NCK * KVR * 64 + off;
    unsigned short* dst = kvpb + (size_t)h * NCK * KVR * 64 + off;
    float v[NCK];
    #pragma unroll
    for (int c2 = 0; c2 < NCK; ++c2) v[c2] = src[(size_t)c2 * KVR * 64];
    float run = 0.f;
    #pragma unroll
    for (int c2 = 0; c2 < NCK; ++c2) {
        dst[(size_t)c2 * KVR * 64] = f2bf(run);
        run += v[c2];
    }
}

// ---------------- Phase C: per-(head,chunk) outputs via MFMA ----------------
__global__ __launch_bounds__(256)
void attn_chunk(const unsigned short* __restrict__ qkv,
                const unsigned short* __restrict__ kvpb,
                unsigned short* __restrict__ attnb)
{
    const int c = blockIdx.x, h = blockIdx.y;
    __shared__ unsigned short q_s[64 * 64];   // phi_q [r][d]
    __shared__ unsigned short k_s[64 * 64];   // phi_k [s][d]
    __shared__ unsigned short p_s[64 * 64];   // masked P bf16 [r][s]
    __shared__ unsigned short vT[KVRP * 64];  // V^T [j][s], row64=ones
    __shared__ unsigned short kvp[KVRP * 64]; // KVp^T_aug [j][d], row64=ksp
    const int tid = threadIdx.x, lane = tid & 63, wave = tid >> 6;
    const int s0 = c * CK;

    #pragma unroll
    for (int part = 0; part < 2; ++part) {
        const int s = (tid >> 3) + part * 32;
        const int d0 = (tid & 7) * 8;
        const size_t base = (size_t)(s0 + s) * (3 * DIM) + (size_t)h * HD + d0;
        ushort8 qq = *(const ushort8*)&qkv[base];
        ushort8 kk = *(const ushort8*)&qkv[base + DIM];
        ushort8 vv = *(const ushort8*)&qkv[base + 2 * DIM];
        short8 qo, ko;
        #pragma unroll
        for (int u = 0; u < 8; ++u) {
            qo[u] = (short)f2bf(phi_fn(bf2f(qq[u])));
            ko[u] = (short)f2bf(phi_fn(bf2f(kk[u])));
        }
        lds_write16(q_s, s, d0, qo);
        lds_write16(k_s, s, d0, ko);
        #pragma unroll
        for (int u = 0; u < 8; ++u)
            lds_write2(vT, d0 + u, s, vv[u]);
    }
    const unsigned short* kv_src = kvpb + (size_t)(h * NCK + c) * KVR * 64;
    for (int idx = tid * 8; idx < KVR * 64; idx += 2048) {
        ushort8 kv8 = *(const ushort8*)&kv_src[idx];
        short8 kv8s;
        #pragma unroll
        for (int u = 0; u < 8; ++u) kv8s[u] = (short)kv8[u];
        lds_write16(kvp, idx >> 6, idx & 63, kv8s);
    }
    if (tid < 64) lds_write2(vT, 64, tid, 0x3F80);
    for (int idx = tid; idx < 15 * 64; idx += 256) {
        lds_write2(vT, 65 + (idx >> 6), idx & 63, 0);
        lds_write2(kvp, 65 + (idx >> 6), idx & 63, 0);
    }
    __syncthreads();

    const int r0 = wave * 16;
    fx4 accp[4] = {};
    #pragma unroll
    for (int ks = 0; ks < 2; ++ks) {
        short8 aq = lds_read_frag(q_s, r0 + (lane & 15), ks * 32 + (lane >> 4) * 8);
        #pragma unroll
        for (int nt = 0; nt < 4; ++nt) {
            short8 bk = lds_read_frag(k_s, nt * 16 + (lane & 15), ks * 32 + (lane >> 4) * 8);
            accp[nt] = __builtin_amdgcn_mfma_f32_16x16x32_bf16(aq, bk, accp[nt], 0, 0, 0);
        }
    }
    #pragma unroll
    for (int nt = 0; nt < 4; ++nt)
        #pragma unroll
        for (int t = 0; t < 4; ++t) {
            const int r = r0 + (lane >> 4) * 4 + t, sc = nt * 16 + (lane & 15);
            lds_write2(p_s, r, sc, (sc <= r) ? f2bf(accp[nt][t]) : (unsigned short)0);
        }
    __syncthreads();

    fx4 acc[5] = {};
    #pragma unroll
    for (int ks = 0; ks < 2; ++ks) {
        short8 ap = lds_read_frag(p_s, r0 + (lane & 15), ks * 32 + (lane >> 4) * 8);
        short8 aq = lds_read_frag(q_s, r0 + (lane & 15), ks * 32 + (lane >> 4) * 8);
        #pragma unroll
        for (int nt = 0; nt < 5; ++nt) {
            short8 bv  = lds_read_frag(vT,  nt * 16 + (lane & 15), ks * 32 + (lane >> 4) * 8);
            short8 bkv = lds_read_frag(kvp, nt * 16 + (lane & 15), ks * 32 + (lane >> 4) * 8);
            acc[nt] = __builtin_amdgcn_mfma_f32_16x16x32_bf16(ap, bv,  acc[nt], 0, 0, 0);
            acc[nt] = __builtin_amdgcn_mfma_f32_16x16x32_bf16(aq, bkv, acc[nt], 0, 0, 0);
        }
    }
    float dinv[4];
    #pragma unroll
    for (int t = 0; t < 4; ++t) {
        const float d = __shfl(acc[4][t], lane & 48, 64);
        dinv[t] = 1.f / (d + 1e-6f);
    }
    #pragma unroll
    for (int nt = 0; nt < 4; ++nt)
        #pragma unroll
        for (int t = 0; t < 4; ++t) {
            const int r = r0 + (lane >> 4) * 4 + t, j = nt * 16 + (lane & 15);
            attnb[(size_t)(s0 + r) * DIM + (size_t)h * HD + j] = f2bf(acc[nt][t] * dinv[t]);
        }
}

extern "C" void kernel_launch(void* const* d_in, const int* in_sizes, int n_in,
                              void* d_out, int out_size, void* d_ws, size_t ws_size,
                              hipStream_t stream)
{
    const float* x     = (const float*)d_in[0];
    const float* W_qkv = (const float*)d_in[2];
    const float* W_out = (const float*)d_in[3];
    float* out = (float*)d_out;

    char* ws = (char*)d_ws;
    size_t off = 0;
    unsigned short* qkvb = (unsigned short*)(ws + off); off += (size_t)SEQ * 3 * DIM * 2;       // 12.6 MB
    unsigned short* xb   = (unsigned short*)(ws + off); off += (size_t)SEQ * DIM * 2;           //  4.2 MB
    float*          kvs  = (float*)         (ws + off); off += (size_t)NH * NCK * KVR * 64 * 4; //  8.5 MB
    unsigned short* kvpb = (unsigned short*)(ws + off); off += (size_t)NH * NCK * KVR * 64 * 2; //  4.3 MB
    unsigned short* wqt  = (unsigned short*)(ws + off); off += (size_t)3 * DIM * DIM * 2;       //  6.3 MB
    unsigned short* wot  = (unsigned short*)(ws + off); off += (size_t)DIM * DIM * 2;           //  2.1 MB
    unsigned short* attnb = xb;   // alias: qkv-GEMM finishes reading xb first (stream order)

    dim3 blk(256);

    to_bf16_vec<<<dim3(SEQ * DIM / 1024), blk, 0, stream>>>(x, xb, SEQ * DIM);
    transpose2_to_bf16<<<dim3(96 * 32 + 32 * 32), blk, 0, stream>>>(W_qkv, wqt, W_out, wot);

    // qkv = x @ W_qkv : M=2048, N=3072, K=1024. BM=128,BN=192 -> 16x16=256 blocks (1/CU)
    gemm_pipe<2, 4, 3, 1><<<dim3(3 * DIM / 192, SEQ / 128), dim3(512), 0, stream>>>(
        xb, wqt, qkvb, SEQ, 3 * DIM, DIM);

    chunk_kv<<<dim3(NCK, NH), blk, 0, stream>>>(qkvb, kvs);
    scan_kv<<<dim3((NH * KVR * 64 + 255) / 256), blk, 0, stream>>>(kvs, kvpb);
    attn_chunk<<<dim3(NCK, NH), blk, 0, stream>>>(qkvb, kvpb, attnb);

    // out = attn @ W_out : M=2048, N=1024, K=1024. BM=128,BN=64 -> 16x16=256 blocks (2/CU)
    gemm_pipe<2, 2, 2, 0><<<dim3(DIM / 64, SEQ / 128), dim3(256), 0, stream>>>(
        attnb, wot, out, SEQ, DIM, DIM);
}

// Round 6
// 58.745 us; speedup vs baseline: 7.1535x; 1.1304x over previous
//
#include <hip/hip_runtime.h>
#include <cstddef>
#include <cstdint>

#define SEQ 2048
#define DIM 1024
#define NH 16
#define HD 64
#define CK 64
#define NCK (SEQ / CK)     // 32 chunks
#define KVR 65             // KV^T rows incl. ksum row
#define KVRP 80            // padded to 5 MFMA tiles

typedef __attribute__((ext_vector_type(8))) short short8;            // 8 bf16
typedef __attribute__((ext_vector_type(8))) unsigned short ushort8;  // 8 raw bf16
typedef __attribute__((ext_vector_type(4))) float fx4;

__device__ __forceinline__ float phi_fn(float x) {
    return x > 0.f ? x + 1.f : __expf(x);   // elu(x)+1
}
__device__ __forceinline__ float bf2f(unsigned short u) {
    return __uint_as_float((unsigned int)u << 16);
}
__device__ __forceinline__ unsigned short f2bf(float f) {
    unsigned int u = __float_as_uint(f);
    unsigned int r = (u + 0x7FFFu + ((u >> 16) & 1u)) >> 16;   // RNE
    return (unsigned short)r;
}

// ---- swizzled LDS helpers: row stride 64 ushort (128 B); byte ^= (row&7)<<4 ----
__device__ __forceinline__ void lds_write16(unsigned short* base, int row, int col, short8 v) {
    int byte = row * 128 + col * 2; byte ^= (row & 7) << 4;
    *(short8*)((char*)base + byte) = v;
}
__device__ __forceinline__ void lds_write2(unsigned short* base, int row, int col, unsigned short v) {
    int byte = row * 128 + col * 2; byte ^= (row & 7) << 4;
    *(unsigned short*)((char*)base + byte) = v;
}
__device__ __forceinline__ short8 lds_read_frag(const unsigned short* base, int row, int kcol) {
    int byte = row * 128 + kcol * 2; byte ^= (row & 7) << 4;
    return *(const short8*)((const char*)base + byte);
}

template<int N> __device__ __forceinline__ void waitv() {
    if constexpr (N == 0)       asm volatile("s_waitcnt vmcnt(0)"  ::: "memory");
    else if constexpr (N == 4)  asm volatile("s_waitcnt vmcnt(4)"  ::: "memory");
    else if constexpr (N == 5)  asm volatile("s_waitcnt vmcnt(5)"  ::: "memory");
    else if constexpr (N == 6)  asm volatile("s_waitcnt vmcnt(6)"  ::: "memory");
    else if constexpr (N == 8)  asm volatile("s_waitcnt vmcnt(8)"  ::: "memory");
    else if constexpr (N == 10) asm volatile("s_waitcnt vmcnt(10)" ::: "memory");
    else if constexpr (N == 12) asm volatile("s_waitcnt vmcnt(12)" ::: "memory");
    else                        asm volatile("s_waitcnt vmcnt(0)"  ::: "memory");
}

// -------- fused prep: x->bf16, W_qkv^T->bf16, W_out^T->bf16 (one launch) --------
__global__ __launch_bounds__(256)
void prep_fused(const float* __restrict__ x, unsigned short* __restrict__ xb,
                const float* __restrict__ W1, unsigned short* __restrict__ WT1,
                const float* __restrict__ W2, unsigned short* __restrict__ WT2)
{
    __shared__ float t[32][33];
    int b = blockIdx.x;
    if (b < 2048) {                       // x -> bf16 : 2048*256*4 = 2M elements
        const int i = (b * 256 + threadIdx.x) * 4;
        float4 v = *(const float4*)&x[i];
        ushort4 o;
        o.x = f2bf(v.x); o.y = f2bf(v.y); o.z = f2bf(v.z); o.w = f2bf(v.w);
        *(ushort4*)&xb[i] = o;
        return;
    }
    b -= 2048;
    const float* W; unsigned short* WT; int N, kb, nb;
    if (b < 96 * 32) {
        W = W1; WT = WT1; N = 3 * DIM;
        nb = (b % 96) * 32; kb = (b / 96) * 32;
    } else {
        b -= 96 * 32;
        W = W2; WT = WT2; N = DIM;
        nb = (b % 32) * 32; kb = (b / 32) * 32;
    }
    const int c = threadIdx.x & 31, r0 = threadIdx.x >> 5;
    #pragma unroll
    for (int i = 0; i < 4; ++i) {
        const int r = r0 + i * 8;
        t[r][c] = W[(size_t)(kb + r) * N + nb + c];
    }
    __syncthreads();
    #pragma unroll
    for (int i = 0; i < 4; ++i) {
        const int r = r0 + i * 8;
        WT[(size_t)(nb + r) * DIM + kb + c] = f2bf(t[c][r]);
    }
}

// ============ 3-slot, 1-barrier/K-step pipelined bf16 MFMA GEMM ============
// C(MxN) = A(MxK) @ BT(NxK)^T.  BM=128, BK=64, BN=WAVES_N*NFRAG*16.
// Prefetch distance 2: stage at iter t targets slot (t+2)%3, whose readers
// (iter t-1) drained lgkmcnt(0) before the single end-of-iteration barrier ->
// the mid-iteration barrier is unnecessary; reads/stage/MFMA of different
// waves overlap within the iteration. Counted vmcnt keeps 1 tile in flight
// across the barrier (T4); setprio (T5); XOR-swizzle both-sides (T2); XCD (T1).
template<int WAVES_M, int WAVES_N, int NFRAG, int OUT_BF16>
__global__ __launch_bounds__(WAVES_M * WAVES_N * 64)
void gemm_pipe(const unsigned short* __restrict__ A,
               const unsigned short* __restrict__ BT,
               void* __restrict__ Cout, int M, int N, int K)
{
    constexpr int BN      = WAVES_N * NFRAG * 16;
    constexpr int THREADS = WAVES_M * WAVES_N * 64;
    constexpr int CHUNK   = THREADS * 16;              // bytes per load-op
    constexpr int ALOADS  = (128 * 64 * 2) / CHUNK;
    constexpr int BLOADS  = (BN * 64 * 2) / CHUNK;
    constexpr int LOADS   = ALOADS + BLOADS;

    __shared__ unsigned short As[3][128 * 64];
    __shared__ unsigned short Bs[3][BN * 64];

    const int tid = threadIdx.x, lane = tid & 63, wave = tid >> 6;
    const int wm = (wave / WAVES_N) * 64;
    const int wn = (wave % WAVES_N) * (NFRAG * 16);

    // XCD-aware block swizzle (nwg divisible by 8)
    int wg = blockIdx.y * gridDim.x + blockIdx.x;
    const int cpx = (gridDim.x * gridDim.y) >> 3;
    wg = (wg & 7) * cpx + (wg >> 3);
    const int bx = wg / gridDim.y;
    const int by = wg % gridDim.y;

    const int m0 = by * 128, n0 = bx * BN;
    const unsigned short* Abase = A + (size_t)m0 * K;
    const unsigned short* Bbase = BT + (size_t)n0 * K;
    const int nt = K >> 6;
    const int fr = lane & 15, fk = (lane >> 4) * 8;

    fx4 acc[4][NFRAG] = {};

    auto STAGE = [&](int slot, int t) {
        const int k0 = t << 6;
        #pragma unroll
        for (int q = 0; q < ALOADS; ++q) {
            const int L = q * CHUNK + tid * 16;                 // linear dest byte
            const int row = L >> 7;
            const int srcb = L ^ ((row & 7) << 4);              // inverse swizzle
            const unsigned short* g = Abase + (size_t)row * K + k0 + ((srcb & 127) >> 1);
            __builtin_amdgcn_global_load_lds(
                (const __attribute__((address_space(1))) void*)g,
                (__attribute__((address_space(3))) void*)((char*)&As[slot][0] + q * CHUNK + wave * 1024),
                16, 0, 0);
        }
        #pragma unroll
        for (int q = 0; q < BLOADS; ++q) {
            const int L = q * CHUNK + tid * 16;
            const int row = L >> 7;
            const int srcb = L ^ ((row & 7) << 4);
            const unsigned short* g = Bbase + (size_t)row * K + k0 + ((srcb & 127) >> 1);
            __builtin_amdgcn_global_load_lds(
                (const __attribute__((address_space(1))) void*)g,
                (__attribute__((address_space(3))) void*)((char*)&Bs[slot][0] + q * CHUNK + wave * 1024),
                16, 0, 0);
        }
    };

    // prologue: distance-2 pipeline, wait for tile 0 (leave tile 1 in flight)
    STAGE(0, 0); STAGE(1, 1);
    waitv<LOADS>();
    __builtin_amdgcn_s_barrier();

    for (int t = 0; t < nt; ++t) {
        const int cur = t % 3;
        short8 a0[4], a1[4], b0[NFRAG], b1[NFRAG];
        #pragma unroll
        for (int i = 0; i < 4; ++i) {
            a0[i] = lds_read_frag(&As[cur][0], wm + i * 16 + fr, fk);
            a1[i] = lds_read_frag(&As[cur][0], wm + i * 16 + fr, 32 + fk);
        }
        #pragma unroll
        for (int j = 0; j < NFRAG; ++j) {
            b0[j] = lds_read_frag(&Bs[cur][0], wn + j * 16 + fr, fk);
            b1[j] = lds_read_frag(&Bs[cur][0], wn + j * 16 + fr, 32 + fk);
        }

        const bool pf = (t + 2 < nt);
        if (pf) STAGE((t + 2) % 3, t + 2);   // slot freed by iter t-1's readers

        asm volatile("s_waitcnt lgkmcnt(0)" ::: "memory");
        __builtin_amdgcn_sched_barrier(0);   // rule #18: pin MFMA below the wait

        __builtin_amdgcn_s_setprio(1);
        #pragma unroll
        for (int i = 0; i < 4; ++i)
            #pragma unroll
            for (int j = 0; j < NFRAG; ++j)
                acc[i][j] = __builtin_amdgcn_mfma_f32_16x16x32_bf16(a0[i], b0[j], acc[i][j], 0, 0, 0);
        #pragma unroll
        for (int i = 0; i < 4; ++i)
            #pragma unroll
            for (int j = 0; j < NFRAG; ++j)
                acc[i][j] = __builtin_amdgcn_mfma_f32_16x16x32_bf16(a1[i], b1[j], acc[i][j], 0, 0, 0);
        __builtin_amdgcn_s_setprio(0);

        // tile t+1 landed; keep t+2 in flight across the barrier
        if (pf) waitv<LOADS>(); else waitv<0>();
        __builtin_amdgcn_s_barrier();
    }

    // C/D layout: col = lane&15, row = (lane>>4)*4 + reg
    const int cr = (lane >> 4) * 4, cc = lane & 15;
    #pragma unroll
    for (int i = 0; i < 4; ++i)
        #pragma unroll
        for (int j = 0; j < NFRAG; ++j) {
            const int m = m0 + wm + i * 16 + cr;
            const int n = n0 + wn + j * 16 + cc;
            #pragma unroll
            for (int r = 0; r < 4; ++r) {
                const float v = acc[i][j][r];
                if (OUT_BF16)
                    ((unsigned short*)Cout)[(size_t)(m + r) * N + n] = f2bf(v);
                else
                    ((float*)Cout)[(size_t)(m + r) * N + n] = v;
            }
        }
}

// ---------------- Phase A: per-(head,chunk) KV^T sums via MFMA ----------------
__global__ __launch_bounds__(256)
void chunk_kv(const unsigned short* __restrict__ qkv, float* __restrict__ kvs)
{
    const int c = blockIdx.x, h = blockIdx.y;
    __shared__ unsigned short kT[64 * 64];    // [i=d][s], swizzled
    __shared__ unsigned short vT[KVRP * 64];  // [j][s], row64=ones, 65-79=0
    const int tid = threadIdx.x, lane = tid & 63, wave = tid >> 6;
    const int s0 = c * CK;

    #pragma unroll
    for (int part = 0; part < 2; ++part) {
        const int s = (tid >> 3) + part * 32;
        const int d0 = (tid & 7) * 8;
        const size_t base = (size_t)(s0 + s) * (3 * DIM) + (size_t)h * HD + d0;
        ushort8 kk = *(const ushort8*)&qkv[base + DIM];
        ushort8 vv = *(const ushort8*)&qkv[base + 2 * DIM];
        #pragma unroll
        for (int u = 0; u < 8; ++u) {
            lds_write2(kT, d0 + u, s, f2bf(phi_fn(bf2f(kk[u]))));
            lds_write2(vT, d0 + u, s, vv[u]);
        }
    }
    if (tid < 64) lds_write2(vT, 64, tid, 0x3F80);   // bf16 1.0
    for (int idx = tid; idx < 15 * 64; idx += 256)
        lds_write2(vT, 65 + (idx >> 6), idx & 63, 0);
    __syncthreads();

    fx4 acc[5] = {};
    #pragma unroll
    for (int ks = 0; ks < 2; ++ks) {
        short8 b = lds_read_frag(kT, wave * 16 + (lane & 15), ks * 32 + (lane >> 4) * 8);
        #pragma unroll
        for (int mt = 0; mt < 5; ++mt) {
            short8 a = lds_read_frag(vT, mt * 16 + (lane & 15), ks * 32 + (lane >> 4) * 8);
            acc[mt] = __builtin_amdgcn_mfma_f32_16x16x32_bf16(a, b, acc[mt], 0, 0, 0);
        }
    }
    float* dst = kvs + (size_t)(h * NCK + c) * KVR * 64;
    const int i = wave * 16 + (lane & 15);
    #pragma unroll
    for (int mt = 0; mt < 5; ++mt)
        #pragma unroll
        for (int t = 0; t < 4; ++t) {
            const int j = mt * 16 + (lane >> 4) * 4 + t;
            if (j < KVR) dst[(size_t)j * 64 + i] = acc[mt][t];
        }
}

// ---------------- Phase B: exclusive prefix scan (ILP loads), bf16 out -------
__global__ __launch_bounds__(256)
void scan_kv(const float* __restrict__ kvs, unsigned short* __restrict__ kvpb)
{
    const int e = blockIdx.x * 256 + threadIdx.x;
    if (e >= NH * KVR * 64) return;
    const int h = e / (KVR * 64), off = e % (KVR * 64);
    const float* src = kvs + (size_t)h * NCK * KVR * 64 + off;
    unsigned short* dst = kvpb + (size_t)h * NCK * KVR * 64 + off;
    float v[NCK];
    #pragma unroll
    for (int c2 = 0; c2 < NCK; ++c2) v[c2] = src[(size_t)c2 * KVR * 64];
    float run = 0.f;
    #pragma unroll
    for (int c2 = 0; c2 < NCK; ++c2) {
        dst[(size_t)c2 * KVR * 64] = f2bf(run);
        run += v[c2];
    }
}

// ---------------- Phase C: per-(head,chunk) outputs via MFMA ----------------
__global__ __launch_bounds__(256)
void attn_chunk(const unsigned short* __restrict__ qkv,
                const unsigned short* __restrict__ kvpb,
                unsigned short* __restrict__ attnb)
{
    const int c = blockIdx.x, h = blockIdx.y;
    __shared__ unsigned short q_s[64 * 64];   // phi_q [r][d]
    __shared__ unsigned short k_s[64 * 64];   // phi_k [s][d]
    __shared__ unsigned short p_s[64 * 64];   // masked P bf16 [r][s]
    __shared__ unsigned short vT[KVRP * 64];  // V^T [j][s], row64=ones
    __shared__ unsigned short kvp[KVRP * 64]; // KVp^T_aug [j][d], row64=ksp
    const int tid = threadIdx.x, lane = tid & 63, wave = tid >> 6;
    const int s0 = c * CK;

    #pragma unroll
    for (int part = 0; part < 2; ++part) {
        const int s = (tid >> 3) + part * 32;
        const int d0 = (tid & 7) * 8;
        const size_t base = (size_t)(s0 + s) * (3 * DIM) + (size_t)h * HD + d0;
        ushort8 qq = *(const ushort8*)&qkv[base];
        ushort8 kk = *(const ushort8*)&qkv[base + DIM];
        ushort8 vv = *(const ushort8*)&qkv[base + 2 * DIM];
        short8 qo, ko;
        #pragma unroll
        for (int u = 0; u < 8; ++u) {
            qo[u] = (short)f2bf(phi_fn(bf2f(qq[u])));
            ko[u] = (short)f2bf(phi_fn(bf2f(kk[u])));
        }
        lds_write16(q_s, s, d0, qo);
        lds_write16(k_s, s, d0, ko);
        #pragma unroll
        for (int u = 0; u < 8; ++u)
            lds_write2(vT, d0 + u, s, vv[u]);
    }
    const unsigned short* kv_src = kvpb + (size_t)(h * NCK + c) * KVR * 64;
    for (int idx = tid * 8; idx < KVR * 64; idx += 2048) {
        ushort8 kv8 = *(const ushort8*)&kv_src[idx];
        short8 kv8s;
        #pragma unroll
        for (int u = 0; u < 8; ++u) kv8s[u] = (short)kv8[u];
        lds_write16(kvp, idx >> 6, idx & 63, kv8s);
    }
    if (tid < 64) lds_write2(vT, 64, tid, 0x3F80);
    for (int idx = tid; idx < 15 * 64; idx += 256) {
        lds_write2(vT, 65 + (idx >> 6), idx & 63, 0);
        lds_write2(kvp, 65 + (idx >> 6), idx & 63, 0);
    }
    __syncthreads();

    const int r0 = wave * 16;
    fx4 accp[4] = {};
    #pragma unroll
    for (int ks = 0; ks < 2; ++ks) {
        short8 aq = lds_read_frag(q_s, r0 + (lane & 15), ks * 32 + (lane >> 4) * 8);
        #pragma unroll
        for (int nt = 0; nt < 4; ++nt) {
            short8 bk = lds_read_frag(k_s, nt * 16 + (lane & 15), ks * 32 + (lane >> 4) * 8);
            accp[nt] = __builtin_amdgcn_mfma_f32_16x16x32_bf16(aq, bk, accp[nt], 0, 0, 0);
        }
    }
    #pragma unroll
    for (int nt = 0; nt < 4; ++nt)
        #pragma unroll
        for (int t = 0; t < 4; ++t) {
            const int r = r0 + (lane >> 4) * 4 + t, sc = nt * 16 + (lane & 15);
            lds_write2(p_s, r, sc, (sc <= r) ? f2bf(accp[nt][t]) : (unsigned short)0);
        }
    __syncthreads();

    fx4 acc[5] = {};
    #pragma unroll
    for (int ks = 0; ks < 2; ++ks) {
        short8 ap = lds_read_frag(p_s, r0 + (lane & 15), ks * 32 + (lane >> 4) * 8);
        short8 aq = lds_read_frag(q_s, r0 + (lane & 15), ks * 32 + (lane >> 4) * 8);
        #pragma unroll
        for (int nt = 0; nt < 5; ++nt) {
            short8 bv  = lds_read_frag(vT,  nt * 16 + (lane & 15), ks * 32 + (lane >> 4) * 8);
            short8 bkv = lds_read_frag(kvp, nt * 16 + (lane & 15), ks * 32 + (lane >> 4) * 8);
            acc[nt] = __builtin_amdgcn_mfma_f32_16x16x32_bf16(ap, bv,  acc[nt], 0, 0, 0);
            acc[nt] = __builtin_amdgcn_mfma_f32_16x16x32_bf16(aq, bkv, acc[nt], 0, 0, 0);
        }
    }
    float dinv[4];
    #pragma unroll
    for (int t = 0; t < 4; ++t) {
        const float d = __shfl(acc[4][t], lane & 48, 64);
        dinv[t] = 1.f / (d + 1e-6f);
    }
    #pragma unroll
    for (int nt = 0; nt < 4; ++nt)
        #pragma unroll
        for (int t = 0; t < 4; ++t) {
            const int r = r0 + (lane >> 4) * 4 + t, j = nt * 16 + (lane & 15);
            attnb[(size_t)(s0 + r) * DIM + (size_t)h * HD + j] = f2bf(acc[nt][t] * dinv[t]);
        }
}

extern "C" void kernel_launch(void* const* d_in, const int* in_sizes, int n_in,
                              void* d_out, int out_size, void* d_ws, size_t ws_size,
                              hipStream_t stream)
{
    const float* x     = (const float*)d_in[0];
    const float* W_qkv = (const float*)d_in[2];
    const float* W_out = (const float*)d_in[3];
    float* out = (float*)d_out;

    char* ws = (char*)d_ws;
    size_t off = 0;
    unsigned short* qkvb = (unsigned short*)(ws + off); off += (size_t)SEQ * 3 * DIM * 2;       // 12.6 MB
    unsigned short* xb   = (unsigned short*)(ws + off); off += (size_t)SEQ * DIM * 2;           //  4.2 MB
    float*          kvs  = (float*)         (ws + off); off += (size_t)NH * NCK * KVR * 64 * 4; //  8.5 MB
    unsigned short* kvpb = (unsigned short*)(ws + off); off += (size_t)NH * NCK * KVR * 64 * 2; //  4.3 MB
    unsigned short* wqt  = (unsigned short*)(ws + off); off += (size_t)3 * DIM * DIM * 2;       //  6.3 MB
    unsigned short* wot  = (unsigned short*)(ws + off); off += (size_t)DIM * DIM * 2;           //  2.1 MB
    unsigned short* attnb = xb;   // alias: qkv-GEMM finishes reading xb first (stream order)

    dim3 blk(256);

    prep_fused<<<dim3(2048 + 96 * 32 + 32 * 32), blk, 0, stream>>>(
        x, xb, W_qkv, wqt, W_out, wot);

    // qkv = x @ W_qkv : M=2048, N=3072, K=1024. BM=128,BN=192 -> 16x16=256 blocks (1/CU)
    gemm_pipe<2, 4, 3, 1><<<dim3(3 * DIM / 192, SEQ / 128), dim3(512), 0, stream>>>(
        xb, wqt, qkvb, SEQ, 3 * DIM, DIM);

    chunk_kv<<<dim3(NCK, NH), blk, 0, stream>>>(qkvb, kvs);
    scan_kv<<<dim3((NH * KVR * 64 + 255) / 256), blk, 0, stream>>>(kvs, kvpb);
    attn_chunk<<<dim3(NCK, NH), blk, 0, stream>>>(qkvb, kvpb, attnb);

    // out = attn @ W_out : M=2048, N=1024, K=1024. BM=128,BN=64 -> 16x16=256 blocks
    gemm_pipe<2, 2, 2, 0><<<dim3(DIM / 64, SEQ / 128), dim3(256), 0, stream>>>(
        attnb, wot, out, SEQ, DIM, DIM);
}